// Round 6
// baseline (354.156 us; speedup 1.0000x reference)
//
#include <hip/hip_runtime.h>

// ---------------------------------------------------------------------------
// SelfAttention: x[2,512,64,64] f32 -> qkv(1x1conv) -> 8-head attn (n=4096,d=64)
// -> proj -> out [2,512,4096] f32.
// R5: 254us total; flash 152us — LDS-pipe-bound (reads/MFMA 1.13, conflicts up).
// R6 flash: NO K/V LDS staging (L2-direct fragments, zero block barriers),
// Wq=32 (4 waves x 32 q, 256thr), P-only LDS with XOR swizzle, XCD-aware
// block swizzle (32 q-blocks per (b,h) pinned to one XCD's L2).
// ---------------------------------------------------------------------------

typedef __attribute__((ext_vector_type(8))) short s16x8;   // 8 bf16 (4 VGPR)
typedef __attribute__((ext_vector_type(4))) float f32x4;   // mfma C/D
typedef __attribute__((ext_vector_type(4))) unsigned short u16x4;

__device__ __forceinline__ unsigned short f2bf(float f) {
  unsigned u = __builtin_bit_cast(unsigned, f);
  u += 0x7fffu + ((u >> 16) & 1u);           // round-to-nearest-even
  return (unsigned short)(u >> 16);
}

__device__ __forceinline__ unsigned cvt_pk_bf16(float lo, float hi) {
  unsigned r;
  asm("v_cvt_pk_bf16_f32 %0, %1, %2" : "=v"(r) : "v"(lo), "v"(hi));
  return r;  // low16 = bf16(lo), high16 = bf16(hi)
}

// ---- kernel 0a: convert qkv_w (1536x512) and proj_w (512x512) f32->bf16 ----
__global__ __launch_bounds__(256) void prep_weights(
    const float* __restrict__ qkv_w, const float* __restrict__ proj_w,
    short* __restrict__ wq, short* __restrict__ wp) {
  int t = blockIdx.x * 256 + threadIdx.x;
  const int NQ = 1536 * 512 / 4;
  if (t < NQ) {
    float4 v = ((const float4*)qkv_w)[t];
    u16x4 o; o[0] = f2bf(v.x); o[1] = f2bf(v.y); o[2] = f2bf(v.z); o[3] = f2bf(v.w);
    ((u16x4*)wq)[t] = o;
  } else {
    int t2 = t - NQ;
    float4 v = ((const float4*)proj_w)[t2];
    u16x4 o; o[0] = f2bf(v.x); o[1] = f2bf(v.y); o[2] = f2bf(v.z); o[3] = f2bf(v.w);
    ((u16x4*)wp)[t2] = o;
  }
}

// ---- kernel 0b: x [b][c=512][n=4096] f32 -> Xt [b][n][c] bf16 ----
__global__ __launch_bounds__(256) void prep_transpose(
    const float* __restrict__ x, short* __restrict__ xt) {
  __shared__ short TL[64 * 72];
  const int b = blockIdx.z, c0 = blockIdx.y * 64, n0 = blockIdx.x * 64;
  const int t = threadIdx.x;
  const int cr = t >> 4, n4 = (t & 15) * 4;
#pragma unroll
  for (int i = 0; i < 4; i++) {
    int c = cr + i * 16;
    float4 v = *(const float4*)(x + ((size_t)(b * 512 + c0 + c)) * 4096 + n0 + n4);
    TL[(n4 + 0) * 72 + c] = (short)f2bf(v.x);
    TL[(n4 + 1) * 72 + c] = (short)f2bf(v.y);
    TL[(n4 + 2) * 72 + c] = (short)f2bf(v.z);
    TL[(n4 + 3) * 72 + c] = (short)f2bf(v.w);
  }
  __syncthreads();
  const int n = t >> 2;
#pragma unroll
  for (int s2 = 0; s2 < 2; s2++) {
    int s = (t & 3) * 2 + s2;
    s16x8 v = *(const s16x8*)&TL[n * 72 + s * 8];
    *(s16x8*)(xt + ((size_t)(b * 4096 + n0 + n)) * 512 + c0 + s * 8) = v;
  }
}

// ---- kernel 1: qkv GEMM. Q,K emitted [n][o] (swapped), V [o][n] (natural).
//      Q additionally pre-scaled by 0.125*log2(e) for the flash exp2 path.
__global__ __launch_bounds__(256) void qkv_gemm(
    const short* __restrict__ wq, const short* __restrict__ xt,
    const float* __restrict__ qkv_b,
    short* __restrict__ qkbuf,   // [b][n][1024]  (Q cols 0..511 scaled, K 512..1023)
    short* __restrict__ vbuf) {  // [b][512][4096]
  __shared__ short Al[128 * 40];
  __shared__ short Bl[128 * 40];
  const int b = blockIdx.z;
  const int m0 = blockIdx.y * 128, n0 = blockIdx.x * 128;
  const bool swapped = (blockIdx.y < 8);
  const int t = threadIdx.x, lane = t & 63, wid = t >> 6;
  const int wr = wid >> 1, wc = wid & 1;
  const int srow = t >> 1, scol = (t & 1) * 16;
  const short* gA = wq + (size_t)(m0 + srow) * 512 + scol;
  const short* gB = xt + ((size_t)(b * 4096 + n0 + srow)) * 512 + scol;
  short* lA = &Al[srow * 40 + scol];
  short* lB = &Bl[srow * 40 + scol];
  const short* As = swapped ? Bl : Al;
  const short* Bs = swapped ? Al : Bl;
  f32x4 acc[4][4] = {};
  for (int ks = 0; ks < 16; ks++) {
    *(s16x8*)lA       = *(const s16x8*)(gA + ks * 32);
    *(s16x8*)(lA + 8) = *(const s16x8*)(gA + ks * 32 + 8);
    *(s16x8*)lB       = *(const s16x8*)(gB + ks * 32);
    *(s16x8*)(lB + 8) = *(const s16x8*)(gB + ks * 32 + 8);
    __syncthreads();
    s16x8 af[4], bf[4];
#pragma unroll
    for (int i = 0; i < 4; i++) {
      af[i] = *(const s16x8*)&As[(wr * 64 + i * 16 + (lane & 15)) * 40 + ((lane >> 4) << 3)];
      bf[i] = *(const s16x8*)&Bs[(wc * 64 + i * 16 + (lane & 15)) * 40 + ((lane >> 4) << 3)];
    }
#pragma unroll
    for (int i = 0; i < 4; i++)
#pragma unroll
      for (int j = 0; j < 4; j++)
        acc[i][j] = __builtin_amdgcn_mfma_f32_16x16x32_bf16(af[i], bf[j], acc[i][j], 0, 0, 0);
    __syncthreads();
  }
  if (!swapped) {                             // V region
#pragma unroll
    for (int i = 0; i < 4; i++)
#pragma unroll
      for (int r = 0; r < 4; r++) {
        int orow = m0 + wr * 64 + i * 16 + ((lane >> 4) << 2) + r;
        float bias = qkv_b[orow];
#pragma unroll
        for (int j = 0; j < 4; j++) {
          int ncol = n0 + wc * 64 + j * 16 + (lane & 15);
          vbuf[((size_t)(b * 512 + orow - 1024)) * 4096 + ncol] = (short)f2bf(acc[i][j][r] + bias);
        }
      }
  } else {                                    // Q/K region: D^T -> [n][o]
    const float qs = (m0 < 512) ? 0.18033688f : 1.0f;   // 0.125 * log2(e) for Q
#pragma unroll
    for (int j = 0; j < 4; j++) {
      int ocol = m0 + wc * 64 + j * 16 + (lane & 15);
      float bias = qkv_b[ocol];
#pragma unroll
      for (int i = 0; i < 4; i++)
#pragma unroll
        for (int r = 0; r < 4; r++) {
          int nrow = n0 + wr * 64 + i * 16 + ((lane >> 4) << 2) + r;
          qkbuf[((size_t)(b * 4096 + nrow)) * 1024 + ocol] = (short)f2bf((acc[i][j][r] + bias) * qs);
        }
    }
  }
}

// ---- kernel 2: flash attention v3 ----
// 4 waves x 32 q (Wq=32), 256 thr, grid 512 (flattened, XCD-swizzled).
// K/V fragments loaded DIRECTLY from global (L2-resident) — no K/V LDS,
// no block barriers. LDS holds only per-wave P [32][64], XOR-swizzled.
// S^T = mfma(K,Q): lane holds S[q=c][k=ni*16+g*4+r] per mi. Softmax in-lane,
// T13 defer-max. O^T = mfma(V,P): all state in-lane at q=c.
__global__ __launch_bounds__(256) void flash_attn(
    const short* __restrict__ qkbuf, const short* __restrict__ vbuf,
    short* __restrict__ aout) {                // [b][n][512] bf16
  __shared__ short Pl[4 * 32 * 64];            // per-wave P, swizzled (16 KB)
  const int t = threadIdx.x, lane = t & 63, wid = t >> 6;
  const int g = lane >> 4, c = lane & 15;
  // XCD swizzle: 32 q-blocks sharing (b,h) land on one XCD (j%8 const -> lid chunk)
  const int j = blockIdx.x;
  const int lid = ((j & 7) << 6) + (j >> 3);   // bijective 0..511
  const int qb = (lid & 31) * 128 + wid * 32;
  const int bh = lid >> 5, b = bh >> 3, h = bh & 7;

  s16x8 qf[2][2];                              // Q pre-scaled by 0.125*log2e
#pragma unroll
  for (int mi = 0; mi < 2; mi++)
#pragma unroll
    for (int kd = 0; kd < 2; kd++)
      qf[mi][kd] = *(const s16x8*)(qkbuf + ((size_t)(b * 4096 + qb + mi * 16 + c)) * 1024
                                   + h * 64 + kd * 32 + g * 8);

  f32x4 oacc[2][4] = {};                       // O^T[d=di*16+g*4+r][q=c] per mi
  float m[2] = {-__builtin_inff(), -__builtin_inff()};
  float l[2] = {0.f, 0.f};

  const short* kbase = qkbuf + ((size_t)(b * 4096 + c)) * 1024 + 512 + h * 64 + g * 8;
  const short* vbase = vbuf + ((size_t)(b * 512 + h * 64 + c)) * 4096 + g * 8;
  short* myP = &Pl[wid * 32 * 64];
  const int sw = (c & 7) << 3;                 // short-index XOR swizzle

  for (int kt = 0; kt < 64; kt++) {
    const int kp0 = kt * 64;
    // ---- issue all K/V fragment loads for this tile (L2-served) ----
    s16x8 kf[4][2], vf[2][4];
#pragma unroll
    for (int ni = 0; ni < 4; ni++)
#pragma unroll
      for (int kd = 0; kd < 2; kd++)
        kf[ni][kd] = *(const s16x8*)(kbase + (size_t)(kp0 + ni * 16) * 1024 + kd * 32);
#pragma unroll
    for (int ks = 0; ks < 2; ks++)
#pragma unroll
      for (int di = 0; di < 4; di++)
        vf[ks][di] = *(const s16x8*)(vbase + (size_t)(di * 16) * 4096 + kp0 + ks * 32);
    // ---- per mi: S^T = K Q^T, softmax, P write ----
#pragma unroll
    for (int mi = 0; mi < 2; mi++) {
      f32x4 st[4] = {};
#pragma unroll
      for (int ni = 0; ni < 4; ni++) {
        st[ni] = __builtin_amdgcn_mfma_f32_16x16x32_bf16(kf[ni][0], qf[mi][0], st[ni], 0, 0, 0);
        st[ni] = __builtin_amdgcn_mfma_f32_16x16x32_bf16(kf[ni][1], qf[mi][1], st[ni], 0, 0, 0);
      }
      float t01 = fmaxf(fmaxf(st[0][0], st[0][1]), fmaxf(st[0][2], st[0][3]));
      float t23 = fmaxf(fmaxf(st[1][0], st[1][1]), fmaxf(st[1][2], st[1][3]));
      float t45 = fmaxf(fmaxf(st[2][0], st[2][1]), fmaxf(st[2][2], st[2][3]));
      float t67 = fmaxf(fmaxf(st[3][0], st[3][1]), fmaxf(st[3][2], st[3][3]));
      float tm = fmaxf(fmaxf(t01, t23), fmaxf(t45, t67));
      tm = fmaxf(tm, __shfl_xor(tm, 16));
      tm = fmaxf(tm, __shfl_xor(tm, 32));      // row max for q=c
      if (!__all(tm <= m[mi] + 8.f)) {         // T13 defer-max
        float mn = fmaxf(m[mi], tm);
        float alpha = exp2f(m[mi] - mn);       // tile 0: exp2(-inf)=0
        m[mi] = mn;
        l[mi] *= alpha;
#pragma unroll
        for (int di = 0; di < 4; di++)
#pragma unroll
          for (int r = 0; r < 4; r++) oacc[mi][di][r] *= alpha;
      }
      float ps = 0.f;
      const int prow = (mi * 16 + c) * 64;
#pragma unroll
      for (int ni = 0; ni < 4; ni++) {
        float p0 = exp2f(st[ni][0] - m[mi]);
        float p1 = exp2f(st[ni][1] - m[mi]);
        float p2 = exp2f(st[ni][2] - m[mi]);
        float p3 = exp2f(st[ni][3] - m[mi]);
        ps += (p0 + p1) + (p2 + p3);
        uint2 w;
        w.x = cvt_pk_bf16(p0, p1);
        w.y = cvt_pk_bf16(p2, p3);
        *(uint2*)&myP[prow + ((ni * 16 + g * 4) ^ sw)] = w;   // P[q=c][k], swizzled
      }
      l[mi] += ps;
    }
    // ---- O^T += V^T P^T (per-wave P; in-wave lgkm ordering, no barrier) ----
#pragma unroll
    for (int ks = 0; ks < 2; ks++) {
      s16x8 pa[2];
#pragma unroll
      for (int mi = 0; mi < 2; mi++)
        pa[mi] = *(const s16x8*)&myP[(mi * 16 + c) * 64 + ((ks * 32 + g * 8) ^ sw)];
#pragma unroll
      for (int di = 0; di < 4; di++) {
#pragma unroll
        for (int mi = 0; mi < 2; mi++)
          oacc[mi][di] = __builtin_amdgcn_mfma_f32_16x16x32_bf16(vf[ks][di], pa[mi], oacc[mi][di], 0, 0, 0);
      }
    }
  }
  // ---- epilogue: all state in-lane at q=c ----
#pragma unroll
  for (int mi = 0; mi < 2; mi++) {
    float lf = l[mi];
    lf += __shfl_xor(lf, 16);
    lf += __shfl_xor(lf, 32);
    float inv = 1.f / lf;
    const size_t orow = ((size_t)(b * 4096 + qb + mi * 16 + c)) * 512 + h * 64;
#pragma unroll
    for (int di = 0; di < 4; di++) {
      uint2 w;
      w.x = cvt_pk_bf16(oacc[mi][di][0] * inv, oacc[mi][di][1] * inv);
      w.y = cvt_pk_bf16(oacc[mi][di][2] * inv, oacc[mi][di][3] * inv);
      *(uint2*)(aout + orow + di * 16 + g * 4) = w;
    }
  }
}

// ---- kernel 3: proj GEMM ----
__global__ __launch_bounds__(256) void proj_gemm(
    const short* __restrict__ wp, const short* __restrict__ aout,
    const float* __restrict__ proj_b, float* __restrict__ out) {
  __shared__ short Al[128 * 40];
  __shared__ short Bl[128 * 40];
  const int b = blockIdx.z;
  const int m0 = blockIdx.y * 128, n0 = blockIdx.x * 128;
  const int t = threadIdx.x, lane = t & 63, wid = t >> 6;
  const int wr = wid >> 1, wc = wid & 1;
  const int srow = t >> 1, scol = (t & 1) * 16;
  const short* gA = wp + (size_t)(m0 + srow) * 512 + scol;
  const short* gB = aout + ((size_t)(b * 4096 + n0 + srow)) * 512 + scol;
  short* lA = &Al[srow * 40 + scol];
  short* lB = &Bl[srow * 40 + scol];
  f32x4 acc[4][4] = {};
  for (int ks = 0; ks < 16; ks++) {
    *(s16x8*)lA       = *(const s16x8*)(gA + ks * 32);
    *(s16x8*)(lA + 8) = *(const s16x8*)(gA + ks * 32 + 8);
    *(s16x8*)lB       = *(const s16x8*)(gB + ks * 32);
    *(s16x8*)(lB + 8) = *(const s16x8*)(gB + ks * 32 + 8);
    __syncthreads();
    s16x8 af[4], bf[4];
#pragma unroll
    for (int i = 0; i < 4; i++) {
      af[i] = *(const s16x8*)&Al[(wr * 64 + i * 16 + (lane & 15)) * 40 + ((lane >> 4) << 3)];
      bf[i] = *(const s16x8*)&Bl[(wc * 64 + i * 16 + (lane & 15)) * 40 + ((lane >> 4) << 3)];
    }
#pragma unroll
    for (int i = 0; i < 4; i++)
#pragma unroll
      for (int j = 0; j < 4; j++)
        acc[i][j] = __builtin_amdgcn_mfma_f32_16x16x32_bf16(af[i], bf[j], acc[i][j], 0, 0, 0);
    __syncthreads();
  }
#pragma unroll
  for (int i = 0; i < 4; i++)
#pragma unroll
    for (int r = 0; r < 4; r++) {
      int orow = m0 + wr * 64 + i * 16 + ((lane >> 4) << 2) + r;
      float bias = proj_b[orow];
#pragma unroll
      for (int j = 0; j < 4; j++) {
        int ncol = n0 + wc * 64 + j * 16 + (lane & 15);
        out[((size_t)(b * 512 + orow)) * 4096 + ncol] = acc[i][j][r] + bias;
      }
    }
}

extern "C" void kernel_launch(void* const* d_in, const int* in_sizes, int n_in,
                              void* d_out, int out_size, void* d_ws, size_t ws_size,
                              hipStream_t stream) {
  const float* x      = (const float*)d_in[0];
  const float* qkv_w  = (const float*)d_in[1];
  const float* qkv_b  = (const float*)d_in[2];
  const float* proj_w = (const float*)d_in[3];
  const float* proj_b = (const float*)d_in[4];
  float* out = (float*)d_out;
  char* ws = (char*)d_ws;
  short* wq = (short*)(ws);
  short* wp = (short*)(ws + 1572864);
  short* xt = (short*)(ws + 2097152);
  short* qk = (short*)(ws + 10485760);
  short* vb = (short*)(ws + 27262976);
  short* ao = (short*)(ws + 35651584);

  prep_weights  <<<1024, 256, 0, stream>>>(qkv_w, proj_w, wq, wp);
  prep_transpose<<<dim3(64, 8, 2), 256, 0, stream>>>(x, xt);
  qkv_gemm      <<<dim3(32, 12, 2), 256, 0, stream>>>(wq, xt, qkv_b, qk, vb);
  flash_attn    <<<512, 256, 0, stream>>>(qk, vb, ao);
  proj_gemm     <<<dim3(32, 4, 2), 256, 0, stream>>>(wp, ao, proj_b, out);
}

// Round 7
// 265.683 us; speedup vs baseline: 1.3330x; 1.3330x over previous
//
#include <hip/hip_runtime.h>

// ---------------------------------------------------------------------------
// SelfAttention: x[2,512,64,64] f32 -> qkv(1x1conv) -> 8-head attn (n=4096,d=64)
// -> proj -> out [2,512,4096] f32.
// R5: flash 152us, LDS-bound w/ 8-way bank conflicts (72-pad + b128 reads).
// R6: L2-direct K/V regressed (uncoalesced 16-row scatter, latency-bound).
// R7 flash: 32x32x16 MFMA (2x arith intensity vs LDS), XOR-swizzled K/V LDS
// (byte ^= (row&7)<<4, conflict-free b128), FULL in-register P via
// cvt_pk_bf16 + permlane32_swap (T12) — zero P LDS traffic. Softmax in-lane
// (q = lane&31, 1 shfl). Defer-max kept. XCD swizzle kept. 4 waves x 32q.
// ---------------------------------------------------------------------------

typedef __attribute__((ext_vector_type(8))) short s16x8;    // 8 bf16 (4 VGPR)
typedef __attribute__((ext_vector_type(4))) float f32x4;    // 16x16 mfma C/D
typedef __attribute__((ext_vector_type(16))) float f32x16;  // 32x32 mfma C/D
typedef __attribute__((ext_vector_type(4))) unsigned short u16x4;
typedef __attribute__((ext_vector_type(2))) unsigned u32x2;
typedef __attribute__((ext_vector_type(4))) unsigned u32x4;

__device__ __forceinline__ unsigned short f2bf(float f) {
  unsigned u = __builtin_bit_cast(unsigned, f);
  u += 0x7fffu + ((u >> 16) & 1u);           // round-to-nearest-even
  return (unsigned short)(u >> 16);
}

__device__ __forceinline__ unsigned cvt_pk_bf16(float lo, float hi) {
  unsigned r;
  asm("v_cvt_pk_bf16_f32 %0, %1, %2" : "=v"(r) : "v"(lo), "v"(hi));
  return r;  // low16 = bf16(lo), high16 = bf16(hi)
}

// ---- kernel 0a: convert qkv_w (1536x512) and proj_w (512x512) f32->bf16 ----
__global__ __launch_bounds__(256) void prep_weights(
    const float* __restrict__ qkv_w, const float* __restrict__ proj_w,
    short* __restrict__ wq, short* __restrict__ wp) {
  int t = blockIdx.x * 256 + threadIdx.x;
  const int NQ = 1536 * 512 / 4;
  if (t < NQ) {
    float4 v = ((const float4*)qkv_w)[t];
    u16x4 o; o[0] = f2bf(v.x); o[1] = f2bf(v.y); o[2] = f2bf(v.z); o[3] = f2bf(v.w);
    ((u16x4*)wq)[t] = o;
  } else {
    int t2 = t - NQ;
    float4 v = ((const float4*)proj_w)[t2];
    u16x4 o; o[0] = f2bf(v.x); o[1] = f2bf(v.y); o[2] = f2bf(v.z); o[3] = f2bf(v.w);
    ((u16x4*)wp)[t2] = o;
  }
}

// ---- kernel 0b: x [b][c=512][n=4096] f32 -> Xt [b][n][c] bf16 ----
__global__ __launch_bounds__(256) void prep_transpose(
    const float* __restrict__ x, short* __restrict__ xt) {
  __shared__ short TL[64 * 72];
  const int b = blockIdx.z, c0 = blockIdx.y * 64, n0 = blockIdx.x * 64;
  const int t = threadIdx.x;
  const int cr = t >> 4, n4 = (t & 15) * 4;
#pragma unroll
  for (int i = 0; i < 4; i++) {
    int c = cr + i * 16;
    float4 v = *(const float4*)(x + ((size_t)(b * 512 + c0 + c)) * 4096 + n0 + n4);
    TL[(n4 + 0) * 72 + c] = (short)f2bf(v.x);
    TL[(n4 + 1) * 72 + c] = (short)f2bf(v.y);
    TL[(n4 + 2) * 72 + c] = (short)f2bf(v.z);
    TL[(n4 + 3) * 72 + c] = (short)f2bf(v.w);
  }
  __syncthreads();
  const int n = t >> 2;
#pragma unroll
  for (int s2 = 0; s2 < 2; s2++) {
    int s = (t & 3) * 2 + s2;
    s16x8 v = *(const s16x8*)&TL[n * 72 + s * 8];
    *(s16x8*)(xt + ((size_t)(b * 4096 + n0 + n)) * 512 + c0 + s * 8) = v;
  }
}

// ---- kernel 1: qkv GEMM. Q,K emitted [n][o] (swapped), V [o][n] (natural).
//      Q additionally pre-scaled by 0.125*log2(e) for the flash exp2 path.
__global__ __launch_bounds__(256) void qkv_gemm(
    const short* __restrict__ wq, const short* __restrict__ xt,
    const float* __restrict__ qkv_b,
    short* __restrict__ qkbuf,   // [b][n][1024]  (Q cols 0..511 scaled, K 512..1023)
    short* __restrict__ vbuf) {  // [b][512][4096]
  __shared__ short Al[128 * 40];
  __shared__ short Bl[128 * 40];
  const int b = blockIdx.z;
  const int m0 = blockIdx.y * 128, n0 = blockIdx.x * 128;
  const bool swapped = (blockIdx.y < 8);
  const int t = threadIdx.x, lane = t & 63, wid = t >> 6;
  const int wr = wid >> 1, wc = wid & 1;
  const int srow = t >> 1, scol = (t & 1) * 16;
  const short* gA = wq + (size_t)(m0 + srow) * 512 + scol;
  const short* gB = xt + ((size_t)(b * 4096 + n0 + srow)) * 512 + scol;
  short* lA = &Al[srow * 40 + scol];
  short* lB = &Bl[srow * 40 + scol];
  const short* As = swapped ? Bl : Al;
  const short* Bs = swapped ? Al : Bl;
  f32x4 acc[4][4] = {};
  for (int ks = 0; ks < 16; ks++) {
    *(s16x8*)lA       = *(const s16x8*)(gA + ks * 32);
    *(s16x8*)(lA + 8) = *(const s16x8*)(gA + ks * 32 + 8);
    *(s16x8*)lB       = *(const s16x8*)(gB + ks * 32);
    *(s16x8*)(lB + 8) = *(const s16x8*)(gB + ks * 32 + 8);
    __syncthreads();
    s16x8 af[4], bf[4];
#pragma unroll
    for (int i = 0; i < 4; i++) {
      af[i] = *(const s16x8*)&As[(wr * 64 + i * 16 + (lane & 15)) * 40 + ((lane >> 4) << 3)];
      bf[i] = *(const s16x8*)&Bs[(wc * 64 + i * 16 + (lane & 15)) * 40 + ((lane >> 4) << 3)];
    }
#pragma unroll
    for (int i = 0; i < 4; i++)
#pragma unroll
      for (int j = 0; j < 4; j++)
        acc[i][j] = __builtin_amdgcn_mfma_f32_16x16x32_bf16(af[i], bf[j], acc[i][j], 0, 0, 0);
    __syncthreads();
  }
  if (!swapped) {                             // V region
#pragma unroll
    for (int i = 0; i < 4; i++)
#pragma unroll
      for (int r = 0; r < 4; r++) {
        int orow = m0 + wr * 64 + i * 16 + ((lane >> 4) << 2) + r;
        float bias = qkv_b[orow];
#pragma unroll
        for (int j = 0; j < 4; j++) {
          int ncol = n0 + wc * 64 + j * 16 + (lane & 15);
          vbuf[((size_t)(b * 512 + orow - 1024)) * 4096 + ncol] = (short)f2bf(acc[i][j][r] + bias);
        }
      }
  } else {                                    // Q/K region: D^T -> [n][o]
    const float qs = (m0 < 512) ? 0.18033688f : 1.0f;   // 0.125 * log2(e) for Q
#pragma unroll
    for (int j = 0; j < 4; j++) {
      int ocol = m0 + wc * 64 + j * 16 + (lane & 15);
      float bias = qkv_b[ocol];
#pragma unroll
      for (int i = 0; i < 4; i++)
#pragma unroll
        for (int r = 0; r < 4; r++) {
          int nrow = n0 + wr * 64 + i * 16 + ((lane >> 4) << 2) + r;
          qkbuf[((size_t)(b * 4096 + nrow)) * 1024 + ocol] = (short)f2bf((acc[i][j][r] + bias) * qs);
        }
    }
  }
}

// ---- kernel 2: flash attention v4 (32x32 MFMA) ----
// 4 waves x 32 q, 256 thr, grid 512 (XCD-swizzled: 2 (b,h) per XCD).
// K/V staged in XOR-swizzled LDS (byte ^= (row&7)<<4 -> conflict-free b128).
// S^T = mfma32(K,Q): lane holds S[kpos=(reg&3)+8*(reg>>2)+4*hi][q=lane&31].
// Softmax in-lane (q=lane&31): 15 fmax + 1 shfl; defer-max THR=8.
// P stays IN REGISTERS: cvt_pk pairs + permlane32_swap build PV B-frags.
// O^T = mfma32(V,P): col=q stays in-lane; 2 barriers/tile only (staging).
__global__ __launch_bounds__(256) void flash_attn(
    const short* __restrict__ qkbuf, const short* __restrict__ vbuf,
    short* __restrict__ aout) {                // [b][n][512] bf16
  __shared__ short Kl[64 * 64];                // [kpos][d], swizzled
  __shared__ short Vl[64 * 64];                // [d][kpos], swizzled
  const int t = threadIdx.x, lane = t & 63, wid = t >> 6;
  const int hi = lane >> 5, q32 = lane & 31;
  const int j = blockIdx.x;
  const int lid = ((j & 7) << 6) + (j >> 3);   // XCD swizzle, bijective 0..511
  const int qb = (lid & 31) * 128 + wid * 32;
  const int bh = lid >> 5, b = bh >> 3, h = bh & 7;

  // Q B-frags: qf[dc] holds Q[qb+q32][h*64 + dc*16 + hi*8 .. +7] (pre-scaled)
  s16x8 qf[4];
  {
    const short* qrow = qkbuf + ((size_t)(b * 4096 + qb + q32)) * 1024 + h * 64 + hi * 8;
#pragma unroll
    for (int dc = 0; dc < 4; dc++) qf[dc] = *(const s16x8*)(qrow + dc * 16);
  }

  f32x16 oacc[2] = {};                         // O^T[d=di*32+(reg&3)+8*(reg>>2)+4*hi][q=q32]
  float m = -__builtin_inff();
  float l = 0.f;                               // per-lane partial (own 32 kpos/tile)

  // staging: thread t stages 32B of K-row and V-row (t>>2), segment t&3
  const int srow = t >> 2;
  const int swz = (srow & 7) << 4;
  const int o0 = ((t & 3) * 32) ^ swz;         // swizzled byte offsets in row
  const int o1 = ((t & 3) * 32 + 16) ^ swz;
  const short* gK = qkbuf + ((size_t)(b * 4096 + srow)) * 1024 + 512 + h * 64 + (t & 3) * 16;
  const short* gV = vbuf + ((size_t)(b * 512 + h * 64 + srow)) * 4096 + (t & 3) * 16;
  char* lKrow = (char*)&Kl[srow * 64];
  char* lVrow = (char*)&Vl[srow * 64];

  s16x8 pk0 = *(const s16x8*)gK, pk1 = *(const s16x8*)(gK + 8);
  s16x8 pv0 = *(const s16x8*)gV, pv1 = *(const s16x8*)(gV + 8);

  for (int kt = 0; kt < 64; kt++) {
    *(s16x8*)(lKrow + o0) = pk0;  *(s16x8*)(lKrow + o1) = pk1;
    *(s16x8*)(lVrow + o0) = pv0;  *(s16x8*)(lVrow + o1) = pv1;
    __syncthreads();
    if (kt < 63) {                             // prefetch next tile under compute
      const short* nK = gK + (size_t)(kt + 1) * 64 * 1024;
      const short* nV = gV + (kt + 1) * 64;
      pk0 = *(const s16x8*)nK;  pk1 = *(const s16x8*)(nK + 8);
      pv0 = *(const s16x8*)nV;  pv1 = *(const s16x8*)(nV + 8);
    }
#pragma unroll
    for (int kb = 0; kb < 2; kb++) {           // two 32-kpos sub-tiles
      // ---- S^T = K Q^T (4 chained mfma over d) ----
      f32x16 st = {};
      const int krow = kb * 32 + q32;
      const int ksw = (krow & 7) << 4;
#pragma unroll
      for (int dc = 0; dc < 4; dc++) {
        s16x8 kf = *(const s16x8*)((char*)&Kl[krow * 64] + ((dc * 32 + hi * 16) ^ ksw));
        st = __builtin_amdgcn_mfma_f32_32x32x16_bf16(kf, qf[dc], st, 0, 0, 0);
      }
      // ---- softmax (in-lane, q=q32; lane owns 16 kpos, partner hi owns rest) ----
      float tm = st[0];
#pragma unroll
      for (int r2 = 1; r2 < 16; r2++) tm = fmaxf(tm, st[r2]);
      tm = fmaxf(tm, __shfl_xor(tm, 32));
      if (!__all(tm <= m + 8.f)) {             // T13 defer-max
        float mn = fmaxf(m, tm);
        float alpha = exp2f(m - mn);           // first tile: exp2(-inf)=0
        m = mn;
        l *= alpha;
#pragma unroll
        for (int di = 0; di < 2; di++)
#pragma unroll
          for (int r2 = 0; r2 < 16; r2++) oacc[di][r2] *= alpha;
      }
      float p[16];
      float ps = 0.f;
#pragma unroll
      for (int r2 = 0; r2 < 16; r2++) { p[r2] = exp2f(st[r2] - m); ps += p[r2]; }
      l += ps;
      // ---- P -> PV B-frags in registers (cvt_pk + permlane32_swap) ----
#pragma unroll
      for (int kh = 0; kh < 2; kh++) {         // kpos 16-halves of this kb
        unsigned A  = cvt_pk_bf16(p[kh * 8 + 0], p[kh * 8 + 1]);
        unsigned Bu = cvt_pk_bf16(p[kh * 8 + 4], p[kh * 8 + 5]);
        unsigned C  = cvt_pk_bf16(p[kh * 8 + 2], p[kh * 8 + 3]);
        unsigned D  = cvt_pk_bf16(p[kh * 8 + 6], p[kh * 8 + 7]);
        u32x2 r0 = __builtin_amdgcn_permlane32_swap(A, Bu, false, false);
        u32x2 r1 = __builtin_amdgcn_permlane32_swap(C, D, false, false);
        u32x4 uu; uu[0] = r0[0]; uu[1] = r1[0]; uu[2] = r0[1]; uu[3] = r1[1];
        s16x8 pf = __builtin_bit_cast(s16x8, uu);
#pragma unroll
        for (int di = 0; di < 2; di++) {
          const int vrow = di * 32 + q32;
          s16x8 vf = *(const s16x8*)((char*)&Vl[vrow * 64]
                       + ((kb * 64 + kh * 32 + hi * 16) ^ ((vrow & 7) << 4)));
          oacc[di] = __builtin_amdgcn_mfma_f32_32x32x16_bf16(vf, pf, oacc[di], 0, 0, 0);
        }
      }
    }
    __syncthreads();   // all waves done with Kl/Vl before restage
  }
  // ---- epilogue: all state in-lane at q=q32 ----
  l += __shfl_xor(l, 32);
  float inv = 1.f / l;
  short* orow = aout + ((size_t)(b * 4096 + qb + q32)) * 512 + h * 64;
#pragma unroll
  for (int di = 0; di < 2; di++)
#pragma unroll
    for (int blk = 0; blk < 4; blk++) {        // d = di*32 + blk*8 + hi*4 + r
      uint2 w;
      w.x = cvt_pk_bf16(oacc[di][blk * 4 + 0] * inv, oacc[di][blk * 4 + 1] * inv);
      w.y = cvt_pk_bf16(oacc[di][blk * 4 + 2] * inv, oacc[di][blk * 4 + 3] * inv);
      *(uint2*)(orow + di * 32 + blk * 8 + hi * 4) = w;
    }
}

// ---- kernel 3: proj GEMM ----
__global__ __launch_bounds__(256) void proj_gemm(
    const short* __restrict__ wp, const short* __restrict__ aout,
    const float* __restrict__ proj_b, float* __restrict__ out) {
  __shared__ short Al[128 * 40];
  __shared__ short Bl[128 * 40];
  const int b = blockIdx.z;
  const int m0 = blockIdx.y * 128, n0 = blockIdx.x * 128;
  const int t = threadIdx.x, lane = t & 63, wid = t >> 6;
  const int wr = wid >> 1, wc = wid & 1;
  const int srow = t >> 1, scol = (t & 1) * 16;
  const short* gA = wp + (size_t)(m0 + srow) * 512 + scol;
  const short* gB = aout + ((size_t)(b * 4096 + n0 + srow)) * 512 + scol;
  short* lA = &Al[srow * 40 + scol];
  short* lB = &Bl[srow * 40 + scol];
  f32x4 acc[4][4] = {};
  for (int ks = 0; ks < 16; ks++) {
    *(s16x8*)lA       = *(const s16x8*)(gA + ks * 32);
    *(s16x8*)(lA + 8) = *(const s16x8*)(gA + ks * 32 + 8);
    *(s16x8*)lB       = *(const s16x8*)(gB + ks * 32);
    *(s16x8*)(lB + 8) = *(const s16x8*)(gB + ks * 32 + 8);
    __syncthreads();
    s16x8 af[4], bf[4];
#pragma unroll
    for (int i = 0; i < 4; i++) {
      af[i] = *(const s16x8*)&Al[(wr * 64 + i * 16 + (lane & 15)) * 40 + ((lane >> 4) << 3)];
      bf[i] = *(const s16x8*)&Bl[(wc * 64 + i * 16 + (lane & 15)) * 40 + ((lane >> 4) << 3)];
    }
#pragma unroll
    for (int i = 0; i < 4; i++)
#pragma unroll
      for (int j = 0; j < 4; j++)
        acc[i][j] = __builtin_amdgcn_mfma_f32_16x16x32_bf16(af[i], bf[j], acc[i][j], 0, 0, 0);
    __syncthreads();
  }
#pragma unroll
  for (int i = 0; i < 4; i++)
#pragma unroll
    for (int r = 0; r < 4; r++) {
      int orow = m0 + wr * 64 + i * 16 + ((lane >> 4) << 2) + r;
      float bias = proj_b[orow];
#pragma unroll
      for (int j = 0; j < 4; j++) {
        int ncol = n0 + wc * 64 + j * 16 + (lane & 15);
        out[((size_t)(b * 512 + orow)) * 4096 + ncol] = acc[i][j][r] + bias;
      }
    }
}

extern "C" void kernel_launch(void* const* d_in, const int* in_sizes, int n_in,
                              void* d_out, int out_size, void* d_ws, size_t ws_size,
                              hipStream_t stream) {
  const float* x      = (const float*)d_in[0];
  const float* qkv_w  = (const float*)d_in[1];
  const float* qkv_b  = (const float*)d_in[2];
  const float* proj_w = (const float*)d_in[3];
  const float* proj_b = (const float*)d_in[4];
  float* out = (float*)d_out;
  char* ws = (char*)d_ws;
  short* wq = (short*)(ws);
  short* wp = (short*)(ws + 1572864);
  short* xt = (short*)(ws + 2097152);
  short* qk = (short*)(ws + 10485760);
  short* vb = (short*)(ws + 27262976);
  short* ao = (short*)(ws + 35651584);

  prep_weights  <<<1024, 256, 0, stream>>>(qkv_w, proj_w, wq, wp);
  prep_transpose<<<dim3(64, 8, 2), 256, 0, stream>>>(x, xt);
  qkv_gemm      <<<dim3(32, 12, 2), 256, 0, stream>>>(wq, xt, qkv_b, qk, vb);
  flash_attn    <<<512, 256, 0, stream>>>(qk, vb, ao);
  proj_gemm     <<<dim3(32, 4, 2), 256, 0, stream>>>(wp, ao, proj_b, out);
}

// Round 9
// 262.010 us; speedup vs baseline: 1.3517x; 1.0140x over previous
//
#include <hip/hip_runtime.h>

// ---------------------------------------------------------------------------
// SelfAttention: x[2,512,64,64] f32 -> qkv(1x1conv) -> 8-head attn (n=4096,d=64)
// -> proj -> out [2,512,4096] f32.
// R7: flash 161us — VALU/dependency-bound at 2 waves/SIMD (grid-capped).
// R8: KV-SPLIT x2 (flash-decoding): grid 1024, 4 blocks/CU -> 4 waves/SIMD.
// Flash writes unnormalized O-partials (bf16) + (m,l) f32; merge_halves
// combines. Pairwise max tree. 32x32 MFMA + XOR-swizzled LDS + in-reg P kept.
// R8 bench: broker timeout, never ran — resubmitting unchanged (R9).
// ---------------------------------------------------------------------------

typedef __attribute__((ext_vector_type(8))) short s16x8;    // 8 bf16 (4 VGPR)
typedef __attribute__((ext_vector_type(4))) float f32x4;    // 16x16 mfma C/D
typedef __attribute__((ext_vector_type(16))) float f32x16;  // 32x32 mfma C/D
typedef __attribute__((ext_vector_type(4))) unsigned short u16x4;
typedef __attribute__((ext_vector_type(2))) unsigned u32x2;
typedef __attribute__((ext_vector_type(4))) unsigned u32x4;

__device__ __forceinline__ unsigned short f2bf(float f) {
  unsigned u = __builtin_bit_cast(unsigned, f);
  u += 0x7fffu + ((u >> 16) & 1u);           // round-to-nearest-even
  return (unsigned short)(u >> 16);
}

__device__ __forceinline__ float bf2f(short s) {
  return __builtin_bit_cast(float, ((unsigned)(unsigned short)s) << 16);
}

__device__ __forceinline__ unsigned cvt_pk_bf16(float lo, float hi) {
  unsigned r;
  asm("v_cvt_pk_bf16_f32 %0, %1, %2" : "=v"(r) : "v"(lo), "v"(hi));
  return r;  // low16 = bf16(lo), high16 = bf16(hi)
}

// ---- kernel 0a: convert qkv_w (1536x512) and proj_w (512x512) f32->bf16 ----
__global__ __launch_bounds__(256) void prep_weights(
    const float* __restrict__ qkv_w, const float* __restrict__ proj_w,
    short* __restrict__ wq, short* __restrict__ wp) {
  int t = blockIdx.x * 256 + threadIdx.x;
  const int NQ = 1536 * 512 / 4;
  if (t < NQ) {
    float4 v = ((const float4*)qkv_w)[t];
    u16x4 o; o[0] = f2bf(v.x); o[1] = f2bf(v.y); o[2] = f2bf(v.z); o[3] = f2bf(v.w);
    ((u16x4*)wq)[t] = o;
  } else {
    int t2 = t - NQ;
    float4 v = ((const float4*)proj_w)[t2];
    u16x4 o; o[0] = f2bf(v.x); o[1] = f2bf(v.y); o[2] = f2bf(v.z); o[3] = f2bf(v.w);
    ((u16x4*)wp)[t2] = o;
  }
}

// ---- kernel 0b: x [b][c=512][n=4096] f32 -> Xt [b][n][c] bf16 ----
__global__ __launch_bounds__(256) void prep_transpose(
    const float* __restrict__ x, short* __restrict__ xt) {
  __shared__ short TL[64 * 72];
  const int b = blockIdx.z, c0 = blockIdx.y * 64, n0 = blockIdx.x * 64;
  const int t = threadIdx.x;
  const int cr = t >> 4, n4 = (t & 15) * 4;
#pragma unroll
  for (int i = 0; i < 4; i++) {
    int c = cr + i * 16;
    float4 v = *(const float4*)(x + ((size_t)(b * 512 + c0 + c)) * 4096 + n0 + n4);
    TL[(n4 + 0) * 72 + c] = (short)f2bf(v.x);
    TL[(n4 + 1) * 72 + c] = (short)f2bf(v.y);
    TL[(n4 + 2) * 72 + c] = (short)f2bf(v.z);
    TL[(n4 + 3) * 72 + c] = (short)f2bf(v.w);
  }
  __syncthreads();
  const int n = t >> 2;
#pragma unroll
  for (int s2 = 0; s2 < 2; s2++) {
    int s = (t & 3) * 2 + s2;
    s16x8 v = *(const s16x8*)&TL[n * 72 + s * 8];
    *(s16x8*)(xt + ((size_t)(b * 4096 + n0 + n)) * 512 + c0 + s * 8) = v;
  }
}

// ---- kernel 1: qkv GEMM. Q,K emitted [n][o] (swapped), V [o][n] (natural).
//      Q additionally pre-scaled by 0.125*log2(e) for the flash exp2 path.
__global__ __launch_bounds__(256) void qkv_gemm(
    const short* __restrict__ wq, const short* __restrict__ xt,
    const float* __restrict__ qkv_b,
    short* __restrict__ qkbuf,   // [b][n][1024]  (Q cols 0..511 scaled, K 512..1023)
    short* __restrict__ vbuf) {  // [b][512][4096]
  __shared__ short Al[128 * 40];
  __shared__ short Bl[128 * 40];
  const int b = blockIdx.z;
  const int m0 = blockIdx.y * 128, n0 = blockIdx.x * 128;
  const bool swapped = (blockIdx.y < 8);
  const int t = threadIdx.x, lane = t & 63, wid = t >> 6;
  const int wr = wid >> 1, wc = wid & 1;
  const int srow = t >> 1, scol = (t & 1) * 16;
  const short* gA = wq + (size_t)(m0 + srow) * 512 + scol;
  const short* gB = xt + ((size_t)(b * 4096 + n0 + srow)) * 512 + scol;
  short* lA = &Al[srow * 40 + scol];
  short* lB = &Bl[srow * 40 + scol];
  const short* As = swapped ? Bl : Al;
  const short* Bs = swapped ? Al : Bl;
  f32x4 acc[4][4] = {};
  for (int ks = 0; ks < 16; ks++) {
    *(s16x8*)lA       = *(const s16x8*)(gA + ks * 32);
    *(s16x8*)(lA + 8) = *(const s16x8*)(gA + ks * 32 + 8);
    *(s16x8*)lB       = *(const s16x8*)(gB + ks * 32);
    *(s16x8*)(lB + 8) = *(const s16x8*)(gB + ks * 32 + 8);
    __syncthreads();
    s16x8 af[4], bf[4];
#pragma unroll
    for (int i = 0; i < 4; i++) {
      af[i] = *(const s16x8*)&As[(wr * 64 + i * 16 + (lane & 15)) * 40 + ((lane >> 4) << 3)];
      bf[i] = *(const s16x8*)&Bs[(wc * 64 + i * 16 + (lane & 15)) * 40 + ((lane >> 4) << 3)];
    }
#pragma unroll
    for (int i = 0; i < 4; i++)
#pragma unroll
      for (int j = 0; j < 4; j++)
        acc[i][j] = __builtin_amdgcn_mfma_f32_16x16x32_bf16(af[i], bf[j], acc[i][j], 0, 0, 0);
    __syncthreads();
  }
  if (!swapped) {                             // V region
#pragma unroll
    for (int i = 0; i < 4; i++)
#pragma unroll
      for (int r = 0; r < 4; r++) {
        int orow = m0 + wr * 64 + i * 16 + ((lane >> 4) << 2) + r;
        float bias = qkv_b[orow];
#pragma unroll
        for (int j = 0; j < 4; j++) {
          int ncol = n0 + wc * 64 + j * 16 + (lane & 15);
          vbuf[((size_t)(b * 512 + orow - 1024)) * 4096 + ncol] = (short)f2bf(acc[i][j][r] + bias);
        }
      }
  } else {                                    // Q/K region: D^T -> [n][o]
    const float qs = (m0 < 512) ? 0.18033688f : 1.0f;   // 0.125 * log2(e) for Q
#pragma unroll
    for (int j = 0; j < 4; j++) {
      int ocol = m0 + wc * 64 + j * 16 + (lane & 15);
      float bias = qkv_b[ocol];
#pragma unroll
      for (int i = 0; i < 4; i++)
#pragma unroll
        for (int r = 0; r < 4; r++) {
          int nrow = n0 + wr * 64 + i * 16 + ((lane >> 4) << 2) + r;
          qkbuf[((size_t)(b * 4096 + nrow)) * 1024 + ocol] = (short)f2bf((acc[i][j][r] + bias) * qs);
        }
    }
  }
}

// ---- kernel 2: flash attention v5 (32x32 MFMA, KV-split x2) ----
// Grid 1024 (XCD-chunked): (b,h) x 32 q-chunks x 2 kv-halves. 4 waves x 32 q.
// Each block: 32 kv-tiles of 64. Writes UNNORMALIZED O (bf16) + (m,l) f32.
__global__ __launch_bounds__(256) void flash_attn(
    const short* __restrict__ qkbuf, const short* __restrict__ vbuf,
    short* __restrict__ opart,       // [2][16][4096][64] bf16
    float* __restrict__ mlbuf) {     // [2][16][4096][2] f32
  __shared__ short Kl[64 * 64];                // [kpos][d], swizzled
  __shared__ short Vl[64 * 64];                // [d][kpos], swizzled
  const int t = threadIdx.x, lane = t & 63, wid = t >> 6;
  const int hi = lane >> 5, q32 = lane & 31;
  const int j = blockIdx.x;
  const int lid = ((j & 7) << 7) + (j >> 3);   // XCD chunking, bijective 0..1023
  const int bh = lid >> 6, b = bh >> 3, h = bh & 7;
  const int rest = lid & 63;
  const int qc = rest >> 1, half = rest & 1;
  const int qb = qc * 128 + wid * 32;
  const int kt0 = half * 32;                   // this block's 32 kv tiles

  // Q B-frags: qf[dc] holds Q[qb+q32][h*64 + dc*16 + hi*8 .. +7] (pre-scaled)
  s16x8 qf[4];
  {
    const short* qrow = qkbuf + ((size_t)(b * 4096 + qb + q32)) * 1024 + h * 64 + hi * 8;
#pragma unroll
    for (int dc = 0; dc < 4; dc++) qf[dc] = *(const s16x8*)(qrow + dc * 16);
  }

  f32x16 oacc[2] = {};                         // O^T[d=di*32+(r&3)+8*(r>>2)+4*hi][q=q32]
  float m = -__builtin_inff();
  float l = 0.f;

  // staging: thread t stages 32B of K-row and V-row (t>>2), segment t&3
  const int srow = t >> 2;
  const int swz = (srow & 7) << 4;
  const int o0 = ((t & 3) * 32) ^ swz;
  const int o1 = ((t & 3) * 32 + 16) ^ swz;
  const short* gK = qkbuf + ((size_t)(b * 4096 + kt0 * 64 + srow)) * 1024 + 512 + h * 64 + (t & 3) * 16;
  const short* gV = vbuf + ((size_t)(b * 512 + h * 64 + srow)) * 4096 + kt0 * 64 + (t & 3) * 16;
  char* lKrow = (char*)&Kl[srow * 64];
  char* lVrow = (char*)&Vl[srow * 64];

  s16x8 pk0 = *(const s16x8*)gK, pk1 = *(const s16x8*)(gK + 8);
  s16x8 pv0 = *(const s16x8*)gV, pv1 = *(const s16x8*)(gV + 8);

  for (int kt = 0; kt < 32; kt++) {
    *(s16x8*)(lKrow + o0) = pk0;  *(s16x8*)(lKrow + o1) = pk1;
    *(s16x8*)(lVrow + o0) = pv0;  *(s16x8*)(lVrow + o1) = pv1;
    __syncthreads();
    if (kt < 31) {                             // prefetch next tile under compute
      const short* nK = gK + (size_t)(kt + 1) * 64 * 1024;
      const short* nV = gV + (kt + 1) * 64;
      pk0 = *(const s16x8*)nK;  pk1 = *(const s16x8*)(nK + 8);
      pv0 = *(const s16x8*)nV;  pv1 = *(const s16x8*)(nV + 8);
    }
#pragma unroll
    for (int kb = 0; kb < 2; kb++) {           // two 32-kpos sub-tiles
      // ---- S^T = K Q^T (4 chained mfma over d) ----
      f32x16 st = {};
      const int krow = kb * 32 + q32;
      const int ksw = (krow & 7) << 4;
#pragma unroll
      for (int dc = 0; dc < 4; dc++) {
        s16x8 kf = *(const s16x8*)((char*)&Kl[krow * 64] + ((dc * 32 + hi * 16) ^ ksw));
        st = __builtin_amdgcn_mfma_f32_32x32x16_bf16(kf, qf[dc], st, 0, 0, 0);
      }
      // ---- softmax (in-lane, q=q32): pairwise max tree ----
      float x0 = fmaxf(st[0], st[1]),  x1 = fmaxf(st[2], st[3]);
      float x2 = fmaxf(st[4], st[5]),  x3 = fmaxf(st[6], st[7]);
      float x4 = fmaxf(st[8], st[9]),  x5 = fmaxf(st[10], st[11]);
      float x6 = fmaxf(st[12], st[13]), x7 = fmaxf(st[14], st[15]);
      x0 = fmaxf(x0, x1); x2 = fmaxf(x2, x3); x4 = fmaxf(x4, x5); x6 = fmaxf(x6, x7);
      x0 = fmaxf(x0, x2); x4 = fmaxf(x4, x6);
      float tm = fmaxf(x0, x4);
      tm = fmaxf(tm, __shfl_xor(tm, 32));
      if (!__all(tm <= m + 8.f)) {             // T13 defer-max
        float mn = fmaxf(m, tm);
        float alpha = exp2f(m - mn);           // first tile: exp2(-inf)=0
        m = mn;
        l *= alpha;
#pragma unroll
        for (int di = 0; di < 2; di++)
#pragma unroll
          for (int r2 = 0; r2 < 16; r2++) oacc[di][r2] *= alpha;
      }
      float p[16];
      float ps = 0.f;
#pragma unroll
      for (int r2 = 0; r2 < 16; r2++) { p[r2] = exp2f(st[r2] - m); ps += p[r2]; }
      l += ps;
      // ---- P -> PV B-frags in registers (cvt_pk + permlane32_swap) ----
#pragma unroll
      for (int kh = 0; kh < 2; kh++) {
        unsigned A  = cvt_pk_bf16(p[kh * 8 + 0], p[kh * 8 + 1]);
        unsigned Bu = cvt_pk_bf16(p[kh * 8 + 4], p[kh * 8 + 5]);
        unsigned C  = cvt_pk_bf16(p[kh * 8 + 2], p[kh * 8 + 3]);
        unsigned D  = cvt_pk_bf16(p[kh * 8 + 6], p[kh * 8 + 7]);
        u32x2 r0 = __builtin_amdgcn_permlane32_swap(A, Bu, false, false);
        u32x2 r1 = __builtin_amdgcn_permlane32_swap(C, D, false, false);
        u32x4 uu; uu[0] = r0[0]; uu[1] = r1[0]; uu[2] = r0[1]; uu[3] = r1[1];
        s16x8 pf = __builtin_bit_cast(s16x8, uu);
#pragma unroll
        for (int di = 0; di < 2; di++) {
          const int vrow = di * 32 + q32;
          s16x8 vf = *(const s16x8*)((char*)&Vl[vrow * 64]
                       + ((kb * 64 + kh * 32 + hi * 16) ^ ((vrow & 7) << 4)));
          oacc[di] = __builtin_amdgcn_mfma_f32_32x32x16_bf16(vf, pf, oacc[di], 0, 0, 0);
        }
      }
    }
    __syncthreads();   // all waves done with Kl/Vl before restage
  }
  // ---- epilogue: write UNNORMALIZED O (bf16) + (m, l) ----
  l += __shfl_xor(l, 32);                      // full row sum (both hi halves)
  const size_t prow = ((size_t)(half * 16 + bh) * 4096 + qb + q32) * 64;
#pragma unroll
  for (int di = 0; di < 2; di++)
#pragma unroll
    for (int blk = 0; blk < 4; blk++) {        // d = di*32 + blk*8 + hi*4 + r
      uint2 w;
      w.x = cvt_pk_bf16(oacc[di][blk * 4 + 0], oacc[di][blk * 4 + 1]);
      w.y = cvt_pk_bf16(oacc[di][blk * 4 + 2], oacc[di][blk * 4 + 3]);
      *(uint2*)(opart + prow + di * 32 + blk * 8 + hi * 4) = w;
    }
  if (hi == 0) {
    const size_t mrow = (size_t)(half * 16 + bh) * 4096 + qb + q32;
    ((float2*)mlbuf)[mrow] = make_float2(m, l);
  }
}

// ---- kernel 2b: merge the two kv-half partials -> aout bf16 [b][n][512] ----
__global__ __launch_bounds__(256) void merge_halves(
    const short* __restrict__ opart, const float* __restrict__ mlbuf,
    short* __restrict__ aout) {
  const int row = blockIdx.x * 256 + threadIdx.x;  // 65536 rows (bh*4096+q)
  const int bh = row >> 12, q = row & 4095, b = bh >> 3, h = bh & 7;
  float2 ml0 = ((const float2*)mlbuf)[row];
  float2 ml1 = ((const float2*)mlbuf)[65536 + row];
  float mm = fmaxf(ml0.x, ml1.x);
  float w0 = exp2f(ml0.x - mm), w1 = exp2f(ml1.x - mm);
  float inv = 1.f / (w0 * ml0.y + w1 * ml1.y);
  w0 *= inv; w1 *= inv;
  const s16x8* r0 = (const s16x8*)(opart + (size_t)row * 64);
  const s16x8* r1 = (const s16x8*)(opart + ((size_t)65536 + row) * 64);
  short* po = aout + ((size_t)(b * 4096 + q)) * 512 + h * 64;
#pragma unroll
  for (int sg = 0; sg < 8; sg++) {
    s16x8 a0 = r0[sg], a1 = r1[sg];
    float v[8];
#pragma unroll
    for (int i = 0; i < 8; i++) v[i] = w0 * bf2f(a0[i]) + w1 * bf2f(a1[i]);
    u32x4 uu;
#pragma unroll
    for (int k = 0; k < 4; k++) uu[k] = cvt_pk_bf16(v[2 * k], v[2 * k + 1]);
    *(s16x8*)(po + sg * 8) = __builtin_bit_cast(s16x8, uu);
  }
}

// ---- kernel 3: proj GEMM ----
__global__ __launch_bounds__(256) void proj_gemm(
    const short* __restrict__ wp, const short* __restrict__ aout,
    const float* __restrict__ proj_b, float* __restrict__ out) {
  __shared__ short Al[128 * 40];
  __shared__ short Bl[128 * 40];
  const int b = blockIdx.z;
  const int m0 = blockIdx.y * 128, n0 = blockIdx.x * 128;
  const int t = threadIdx.x, lane = t & 63, wid = t >> 6;
  const int wr = wid >> 1, wc = wid & 1;
  const int srow = t >> 1, scol = (t & 1) * 16;
  const short* gA = wp + (size_t)(m0 + srow) * 512 + scol;
  const short* gB = aout + ((size_t)(b * 4096 + n0 + srow)) * 512 + scol;
  short* lA = &Al[srow * 40 + scol];
  short* lB = &Bl[srow * 40 + scol];
  f32x4 acc[4][4] = {};
  for (int ks = 0; ks < 16; ks++) {
    *(s16x8*)lA       = *(const s16x8*)(gA + ks * 32);
    *(s16x8*)(lA + 8) = *(const s16x8*)(gA + ks * 32 + 8);
    *(s16x8*)lB       = *(const s16x8*)(gB + ks * 32);
    *(s16x8*)(lB + 8) = *(const s16x8*)(gB + ks * 32 + 8);
    __syncthreads();
    s16x8 af[4], bf[4];
#pragma unroll
    for (int i = 0; i < 4; i++) {
      af[i] = *(const s16x8*)&Al[(wr * 64 + i * 16 + (lane & 15)) * 40 + ((lane >> 4) << 3)];
      bf[i] = *(const s16x8*)&Bl[(wc * 64 + i * 16 + (lane & 15)) * 40 + ((lane >> 4) << 3)];
    }
#pragma unroll
    for (int i = 0; i < 4; i++)
#pragma unroll
      for (int j = 0; j < 4; j++)
        acc[i][j] = __builtin_amdgcn_mfma_f32_16x16x32_bf16(af[i], bf[j], acc[i][j], 0, 0, 0);
    __syncthreads();
  }
#pragma unroll
  for (int i = 0; i < 4; i++)
#pragma unroll
    for (int r = 0; r < 4; r++) {
      int orow = m0 + wr * 64 + i * 16 + ((lane >> 4) << 2) + r;
      float bias = proj_b[orow];
#pragma unroll
      for (int j = 0; j < 4; j++) {
        int ncol = n0 + wc * 64 + j * 16 + (lane & 15);
        out[((size_t)(b * 512 + orow)) * 4096 + ncol] = acc[i][j][r] + bias;
      }
    }
}

extern "C" void kernel_launch(void* const* d_in, const int* in_sizes, int n_in,
                              void* d_out, int out_size, void* d_ws, size_t ws_size,
                              hipStream_t stream) {
  const float* x      = (const float*)d_in[0];
  const float* qkv_w  = (const float*)d_in[1];
  const float* qkv_b  = (const float*)d_in[2];
  const float* proj_w = (const float*)d_in[3];
  const float* proj_b = (const float*)d_in[4];
  float* out = (float*)d_out;
  char* ws = (char*)d_ws;
  // ws layout (bytes): wq 1.5M | wp 0.5M | xt 8M | qk 16M | v 8M | ao 8M |
  //                    opart 16M | ml 1M  = ~59 MiB
  short* wq = (short*)(ws);
  short* wp = (short*)(ws + 1572864);
  short* xt = (short*)(ws + 2097152);
  short* qk = (short*)(ws + 10485760);
  short* vb = (short*)(ws + 27262976);
  short* ao = (short*)(ws + 35651584);
  short* op = (short*)(ws + 44040192);
  float* ml = (float*)(ws + 60817408);

  prep_weights  <<<1024, 256, 0, stream>>>(qkv_w, proj_w, wq, wp);
  prep_transpose<<<dim3(64, 8, 2), 256, 0, stream>>>(x, xt);
  qkv_gemm      <<<dim3(32, 12, 2), 256, 0, stream>>>(wq, xt, qkv_b, qk, vb);
  flash_attn    <<<1024, 256, 0, stream>>>(qk, vb, op, ml);
  merge_halves  <<<256, 256, 0, stream>>>(op, ml, ao);
  proj_gemm     <<<dim3(32, 4, 2), 256, 0, stream>>>(wp, ao, proj_b, out);
}

// Round 10
// 254.898 us; speedup vs baseline: 1.3894x; 1.0279x over previous
//
#include <hip/hip_runtime.h>

// ---------------------------------------------------------------------------
// SelfAttention: x[2,512,64,64] f32 -> qkv(1x1conv) -> 8-head attn (n=4096,d=64)
// -> proj -> out [2,512,4096] f32.
// R9: flash 150us; not occupancy-bound (KV-split x2 bought only 7%).
// R10 flash: global_load_lds staging (pre-swizzled source, linear LDS dest),
// double-buffered LDS + ONE __syncthreads per tile, s_setprio around MFMA.
// Everything else (32x32 MFMA, in-reg P, defer-max, split+merge) unchanged.
// ---------------------------------------------------------------------------

#include <stdint.h>

typedef __attribute__((ext_vector_type(8))) short s16x8;    // 8 bf16 (4 VGPR)
typedef __attribute__((ext_vector_type(4))) float f32x4;    // 16x16 mfma C/D
typedef __attribute__((ext_vector_type(16))) float f32x16;  // 32x32 mfma C/D
typedef __attribute__((ext_vector_type(4))) unsigned short u16x4;
typedef __attribute__((ext_vector_type(2))) unsigned u32x2;
typedef __attribute__((ext_vector_type(4))) unsigned u32x4;

__device__ __forceinline__ unsigned short f2bf(float f) {
  unsigned u = __builtin_bit_cast(unsigned, f);
  u += 0x7fffu + ((u >> 16) & 1u);           // round-to-nearest-even
  return (unsigned short)(u >> 16);
}

__device__ __forceinline__ float bf2f(short s) {
  return __builtin_bit_cast(float, ((unsigned)(unsigned short)s) << 16);
}

__device__ __forceinline__ unsigned cvt_pk_bf16(float lo, float hi) {
  unsigned r;
  asm("v_cvt_pk_bf16_f32 %0, %1, %2" : "=v"(r) : "v"(lo), "v"(hi));
  return r;  // low16 = bf16(lo), high16 = bf16(hi)
}

// async global->LDS, 16B per lane; LDS dest = wave-uniform base + lane*16
__device__ __forceinline__ void gl_lds16(const void* g, void* l) {
  auto gp = reinterpret_cast<const __attribute__((address_space(1))) char*>(
      reinterpret_cast<uintptr_t>(g));
  auto lp = reinterpret_cast<__attribute__((address_space(3))) char*>(
      reinterpret_cast<uintptr_t>(l));
  __builtin_amdgcn_global_load_lds(gp, lp, 16, 0, 0);
}

// ---- kernel 0a: convert qkv_w (1536x512) and proj_w (512x512) f32->bf16 ----
__global__ __launch_bounds__(256) void prep_weights(
    const float* __restrict__ qkv_w, const float* __restrict__ proj_w,
    short* __restrict__ wq, short* __restrict__ wp) {
  int t = blockIdx.x * 256 + threadIdx.x;
  const int NQ = 1536 * 512 / 4;
  if (t < NQ) {
    float4 v = ((const float4*)qkv_w)[t];
    u16x4 o; o[0] = f2bf(v.x); o[1] = f2bf(v.y); o[2] = f2bf(v.z); o[3] = f2bf(v.w);
    ((u16x4*)wq)[t] = o;
  } else {
    int t2 = t - NQ;
    float4 v = ((const float4*)proj_w)[t2];
    u16x4 o; o[0] = f2bf(v.x); o[1] = f2bf(v.y); o[2] = f2bf(v.z); o[3] = f2bf(v.w);
    ((u16x4*)wp)[t2] = o;
  }
}

// ---- kernel 0b: x [b][c=512][n=4096] f32 -> Xt [b][n][c] bf16 ----
__global__ __launch_bounds__(256) void prep_transpose(
    const float* __restrict__ x, short* __restrict__ xt) {
  __shared__ short TL[64 * 72];
  const int b = blockIdx.z, c0 = blockIdx.y * 64, n0 = blockIdx.x * 64;
  const int t = threadIdx.x;
  const int cr = t >> 4, n4 = (t & 15) * 4;
#pragma unroll
  for (int i = 0; i < 4; i++) {
    int c = cr + i * 16;
    float4 v = *(const float4*)(x + ((size_t)(b * 512 + c0 + c)) * 4096 + n0 + n4);
    TL[(n4 + 0) * 72 + c] = (short)f2bf(v.x);
    TL[(n4 + 1) * 72 + c] = (short)f2bf(v.y);
    TL[(n4 + 2) * 72 + c] = (short)f2bf(v.z);
    TL[(n4 + 3) * 72 + c] = (short)f2bf(v.w);
  }
  __syncthreads();
  const int n = t >> 2;
#pragma unroll
  for (int s2 = 0; s2 < 2; s2++) {
    int s = (t & 3) * 2 + s2;
    s16x8 v = *(const s16x8*)&TL[n * 72 + s * 8];
    *(s16x8*)(xt + ((size_t)(b * 4096 + n0 + n)) * 512 + c0 + s * 8) = v;
  }
}

// ---- kernel 1: qkv GEMM. Q,K emitted [n][o] (swapped), V [o][n] (natural).
//      Q additionally pre-scaled by 0.125*log2(e) for the flash exp2 path.
__global__ __launch_bounds__(256) void qkv_gemm(
    const short* __restrict__ wq, const short* __restrict__ xt,
    const float* __restrict__ qkv_b,
    short* __restrict__ qkbuf,   // [b][n][1024]  (Q cols 0..511 scaled, K 512..1023)
    short* __restrict__ vbuf) {  // [b][512][4096]
  __shared__ short Al[128 * 40];
  __shared__ short Bl[128 * 40];
  const int b = blockIdx.z;
  const int m0 = blockIdx.y * 128, n0 = blockIdx.x * 128;
  const bool swapped = (blockIdx.y < 8);
  const int t = threadIdx.x, lane = t & 63, wid = t >> 6;
  const int wr = wid >> 1, wc = wid & 1;
  const int srow = t >> 1, scol = (t & 1) * 16;
  const short* gA = wq + (size_t)(m0 + srow) * 512 + scol;
  const short* gB = xt + ((size_t)(b * 4096 + n0 + srow)) * 512 + scol;
  short* lA = &Al[srow * 40 + scol];
  short* lB = &Bl[srow * 40 + scol];
  const short* As = swapped ? Bl : Al;
  const short* Bs = swapped ? Al : Bl;
  f32x4 acc[4][4] = {};
  for (int ks = 0; ks < 16; ks++) {
    *(s16x8*)lA       = *(const s16x8*)(gA + ks * 32);
    *(s16x8*)(lA + 8) = *(const s16x8*)(gA + ks * 32 + 8);
    *(s16x8*)lB       = *(const s16x8*)(gB + ks * 32);
    *(s16x8*)(lB + 8) = *(const s16x8*)(gB + ks * 32 + 8);
    __syncthreads();
    s16x8 af[4], bf[4];
#pragma unroll
    for (int i = 0; i < 4; i++) {
      af[i] = *(const s16x8*)&As[(wr * 64 + i * 16 + (lane & 15)) * 40 + ((lane >> 4) << 3)];
      bf[i] = *(const s16x8*)&Bs[(wc * 64 + i * 16 + (lane & 15)) * 40 + ((lane >> 4) << 3)];
    }
#pragma unroll
    for (int i = 0; i < 4; i++)
#pragma unroll
      for (int j = 0; j < 4; j++)
        acc[i][j] = __builtin_amdgcn_mfma_f32_16x16x32_bf16(af[i], bf[j], acc[i][j], 0, 0, 0);
    __syncthreads();
  }
  if (!swapped) {                             // V region
#pragma unroll
    for (int i = 0; i < 4; i++)
#pragma unroll
      for (int r = 0; r < 4; r++) {
        int orow = m0 + wr * 64 + i * 16 + ((lane >> 4) << 2) + r;
        float bias = qkv_b[orow];
#pragma unroll
        for (int j = 0; j < 4; j++) {
          int ncol = n0 + wc * 64 + j * 16 + (lane & 15);
          vbuf[((size_t)(b * 512 + orow - 1024)) * 4096 + ncol] = (short)f2bf(acc[i][j][r] + bias);
        }
      }
  } else {                                    // Q/K region: D^T -> [n][o]
    const float qs = (m0 < 512) ? 0.18033688f : 1.0f;   // 0.125 * log2(e) for Q
#pragma unroll
    for (int j = 0; j < 4; j++) {
      int ocol = m0 + wc * 64 + j * 16 + (lane & 15);
      float bias = qkv_b[ocol];
#pragma unroll
      for (int i = 0; i < 4; i++)
#pragma unroll
        for (int r = 0; r < 4; r++) {
          int nrow = n0 + wr * 64 + i * 16 + ((lane >> 4) << 2) + r;
          qkbuf[((size_t)(b * 4096 + nrow)) * 1024 + ocol] = (short)f2bf((acc[i][j][r] + bias) * qs);
        }
    }
  }
}

// ---- kernel 2: flash attention v6 (dbuf + global_load_lds, 1 barrier/tile) ----
// Grid 1024 (XCD-chunked): (b,h) x 32 q-chunks x 2 kv-halves. 4 waves x 32 q.
// LDS content at [row][col] = src[row][col ^ ((row&7)<<4)] (pre-swizzled source,
// linear dest via global_load_lds); reads use the same XOR -> identical layout
// to the passing R9 kernel.
__global__ __launch_bounds__(256) void flash_attn(
    const short* __restrict__ qkbuf, const short* __restrict__ vbuf,
    short* __restrict__ opart,       // [2][16][4096][64] bf16
    float* __restrict__ mlbuf) {     // [2][16][4096][2] f32
  __shared__ short Kl[2][64 * 64];             // [buf][kpos][d]
  __shared__ short Vl[2][64 * 64];             // [buf][d][kpos]
  const int t = threadIdx.x, lane = t & 63, wid = t >> 6;
  const int hi = lane >> 5, q32 = lane & 31;
  const int j = blockIdx.x;
  const int lid = ((j & 7) << 7) + (j >> 3);   // XCD chunking, bijective 0..1023
  const int bh = lid >> 6, b = bh >> 3, h = bh & 7;
  const int rest = lid & 63;
  const int qc = rest >> 1, half = rest & 1;
  const int qb = qc * 128 + wid * 32;
  const int kt0 = half * 32;                   // this block's 32 kv tiles

  // Q B-frags: qf[dc] holds Q[qb+q32][h*64 + dc*16 + hi*8 .. +7] (pre-scaled)
  s16x8 qf[4];
  {
    const short* qrow = qkbuf + ((size_t)(b * 4096 + qb + q32)) * 1024 + h * 64 + hi * 8;
#pragma unroll
    for (int dc = 0; dc < 4; dc++) qf[dc] = *(const s16x8*)(qrow + dc * 16);
  }

  f32x16 oacc[2] = {};                         // O^T[d=di*32+(r&3)+8*(r>>2)+4*hi][q=q32]
  float m = -__builtin_inff();
  float l = 0.f;

  // staging: wave covers rows [wid*16, wid*16+16); lane -> row wid*16+i*8+(lane>>3),
  // 16B seg (lane&7). Source col pre-swizzled by ^((row&7)<<4) = ^((lane>>3)<<4).
  const int lrow = lane >> 3;
  const int lcolb = ((lane & 7) << 4) ^ (lrow << 4);
  const char* kp0 = (const char*)(qkbuf + ((size_t)(b * 4096 + kt0 * 64 + wid * 16 + lrow)) * 1024
                                  + 512 + h * 64) + lcolb;
  const char* kp1 = kp0 + 8 * 2048;            // +8 K rows (global row stride 2048B)
  const char* vp0 = (const char*)(vbuf + ((size_t)(b * 512 + h * 64 + wid * 16 + lrow)) * 4096
                                  + kt0 * 64) + lcolb;
  const char* vp1 = vp0 + 8 * 8192;            // +8 V rows (global row stride 8192B)

#define ISSUE_TILE(bi)                                                      \
  do {                                                                      \
    gl_lds16(kp0, &Kl[bi][(wid * 16 + 0) * 64]);                            \
    gl_lds16(kp1, &Kl[bi][(wid * 16 + 8) * 64]);                            \
    gl_lds16(vp0, &Vl[bi][(wid * 16 + 0) * 64]);                            \
    gl_lds16(vp1, &Vl[bi][(wid * 16 + 8) * 64]);                            \
    kp0 += 131072; kp1 += 131072; vp0 += 128; vp1 += 128;                   \
  } while (0)

  const int ksw = (q32 & 7) << 4;              // read swizzle (rows ≡ q32 mod 8)

  auto do_tile = [&](const short* Klb, const short* Vlb) {
#pragma unroll
    for (int kb = 0; kb < 2; kb++) {           // two 32-kpos sub-tiles
      // ---- S^T = K Q^T (4 chained mfma over d) ----
      f32x16 st = {};
      const char* kr = (const char*)(Klb + (kb * 32 + q32) * 64);
      __builtin_amdgcn_s_setprio(1);
#pragma unroll
      for (int dc = 0; dc < 4; dc++) {
        s16x8 kf = *(const s16x8*)(kr + ((dc * 32 + hi * 16) ^ ksw));
        st = __builtin_amdgcn_mfma_f32_32x32x16_bf16(kf, qf[dc], st, 0, 0, 0);
      }
      __builtin_amdgcn_s_setprio(0);
      // ---- softmax (in-lane, q=q32): pairwise max tree ----
      float x0 = fmaxf(st[0], st[1]),  x1 = fmaxf(st[2], st[3]);
      float x2 = fmaxf(st[4], st[5]),  x3 = fmaxf(st[6], st[7]);
      float x4 = fmaxf(st[8], st[9]),  x5 = fmaxf(st[10], st[11]);
      float x6 = fmaxf(st[12], st[13]), x7 = fmaxf(st[14], st[15]);
      x0 = fmaxf(x0, x1); x2 = fmaxf(x2, x3); x4 = fmaxf(x4, x5); x6 = fmaxf(x6, x7);
      x0 = fmaxf(x0, x2); x4 = fmaxf(x4, x6);
      float tm = fmaxf(x0, x4);
      tm = fmaxf(tm, __shfl_xor(tm, 32));
      if (!__all(tm <= m + 8.f)) {             // T13 defer-max
        float mn = fmaxf(m, tm);
        float alpha = exp2f(m - mn);           // first tile: exp2(-inf)=0
        m = mn;
        l *= alpha;
#pragma unroll
        for (int di = 0; di < 2; di++)
#pragma unroll
          for (int r2 = 0; r2 < 16; r2++) oacc[di][r2] *= alpha;
      }
      float p[16];
      float ps = 0.f;
#pragma unroll
      for (int r2 = 0; r2 < 16; r2++) { p[r2] = exp2f(st[r2] - m); ps += p[r2]; }
      l += ps;
      // ---- P -> PV B-frags in registers (cvt_pk + permlane32_swap) ----
#pragma unroll
      for (int kh = 0; kh < 2; kh++) {
        unsigned A  = cvt_pk_bf16(p[kh * 8 + 0], p[kh * 8 + 1]);
        unsigned Bu = cvt_pk_bf16(p[kh * 8 + 4], p[kh * 8 + 5]);
        unsigned C  = cvt_pk_bf16(p[kh * 8 + 2], p[kh * 8 + 3]);
        unsigned D  = cvt_pk_bf16(p[kh * 8 + 6], p[kh * 8 + 7]);
        u32x2 r0 = __builtin_amdgcn_permlane32_swap(A, Bu, false, false);
        u32x2 r1 = __builtin_amdgcn_permlane32_swap(C, D, false, false);
        u32x4 uu; uu[0] = r0[0]; uu[1] = r1[0]; uu[2] = r0[1]; uu[3] = r1[1];
        s16x8 pf = __builtin_bit_cast(s16x8, uu);
        __builtin_amdgcn_s_setprio(1);
#pragma unroll
        for (int di = 0; di < 2; di++) {
          const char* vr = (const char*)(Vlb + (di * 32 + q32) * 64);
          s16x8 vf = *(const s16x8*)(vr + ((kb * 64 + kh * 32 + hi * 16) ^ ksw));
          oacc[di] = __builtin_amdgcn_mfma_f32_32x32x16_bf16(vf, pf, oacc[di], 0, 0, 0);
        }
        __builtin_amdgcn_s_setprio(0);
      }
    }
  };

  ISSUE_TILE(0);                               // tile 0 -> buf0
#pragma unroll 1
  for (int it = 0; it < 16; it++) {
    __syncthreads();                           // buf0 tile ready; prior reads of buf1 done
    ISSUE_TILE(1);                             // tile 2*it+1 -> buf1 (in flight under compute)
    do_tile(Kl[0], Vl[0]);
    __syncthreads();                           // buf1 tile ready; prior reads of buf0 done
    if (it < 15) ISSUE_TILE(0);                // tile 2*it+2 -> buf0
    do_tile(Kl[1], Vl[1]);
  }
#undef ISSUE_TILE

  // ---- epilogue: write UNNORMALIZED O (bf16) + (m, l) ----
  l += __shfl_xor(l, 32);                      // full row sum (both hi halves)
  const size_t prow = ((size_t)(half * 16 + bh) * 4096 + qb + q32) * 64;
#pragma unroll
  for (int di = 0; di < 2; di++)
#pragma unroll
    for (int blk = 0; blk < 4; blk++) {        // d = di*32 + blk*8 + hi*4 + r
      uint2 w;
      w.x = cvt_pk_bf16(oacc[di][blk * 4 + 0], oacc[di][blk * 4 + 1]);
      w.y = cvt_pk_bf16(oacc[di][blk * 4 + 2], oacc[di][blk * 4 + 3]);
      *(uint2*)(opart + prow + di * 32 + blk * 8 + hi * 4) = w;
    }
  if (hi == 0) {
    const size_t mrow = (size_t)(half * 16 + bh) * 4096 + qb + q32;
    ((float2*)mlbuf)[mrow] = make_float2(m, l);
  }
}

// ---- kernel 2b: merge the two kv-half partials -> aout bf16 [b][n][512] ----
__global__ __launch_bounds__(256) void merge_halves(
    const short* __restrict__ opart, const float* __restrict__ mlbuf,
    short* __restrict__ aout) {
  const int row = blockIdx.x * 256 + threadIdx.x;  // 65536 rows (bh*4096+q)
  const int bh = row >> 12, q = row & 4095, b = bh >> 3, h = bh & 7;
  float2 ml0 = ((const float2*)mlbuf)[row];
  float2 ml1 = ((const float2*)mlbuf)[65536 + row];
  float mm = fmaxf(ml0.x, ml1.x);
  float w0 = exp2f(ml0.x - mm), w1 = exp2f(ml1.x - mm);
  float inv = 1.f / (w0 * ml0.y + w1 * ml1.y);
  w0 *= inv; w1 *= inv;
  const s16x8* r0 = (const s16x8*)(opart + (size_t)row * 64);
  const s16x8* r1 = (const s16x8*)(opart + ((size_t)65536 + row) * 64);
  short* po = aout + ((size_t)(b * 4096 + q)) * 512 + h * 64;
#pragma unroll
  for (int sg = 0; sg < 8; sg++) {
    s16x8 a0 = r0[sg], a1 = r1[sg];
    float v[8];
#pragma unroll
    for (int i = 0; i < 8; i++) v[i] = w0 * bf2f(a0[i]) + w1 * bf2f(a1[i]);
    u32x4 uu;
#pragma unroll
    for (int k = 0; k < 4; k++) uu[k] = cvt_pk_bf16(v[2 * k], v[2 * k + 1]);
    *(s16x8*)(po + sg * 8) = __builtin_bit_cast(s16x8, uu);
  }
}

// ---- kernel 3: proj GEMM ----
__global__ __launch_bounds__(256) void proj_gemm(
    const short* __restrict__ wp, const short* __restrict__ aout,
    const float* __restrict__ proj_b, float* __restrict__ out) {
  __shared__ short Al[128 * 40];
  __shared__ short Bl[128 * 40];
  const int b = blockIdx.z;
  const int m0 = blockIdx.y * 128, n0 = blockIdx.x * 128;
  const int t = threadIdx.x, lane = t & 63, wid = t >> 6;
  const int wr = wid >> 1, wc = wid & 1;
  const int srow = t >> 1, scol = (t & 1) * 16;
  const short* gA = wp + (size_t)(m0 + srow) * 512 + scol;
  const short* gB = aout + ((size_t)(b * 4096 + n0 + srow)) * 512 + scol;
  short* lA = &Al[srow * 40 + scol];
  short* lB = &Bl[srow * 40 + scol];
  f32x4 acc[4][4] = {};
  for (int ks = 0; ks < 16; ks++) {
    *(s16x8*)lA       = *(const s16x8*)(gA + ks * 32);
    *(s16x8*)(lA + 8) = *(const s16x8*)(gA + ks * 32 + 8);
    *(s16x8*)lB       = *(const s16x8*)(gB + ks * 32);
    *(s16x8*)(lB + 8) = *(const s16x8*)(gB + ks * 32 + 8);
    __syncthreads();
    s16x8 af[4], bf[4];
#pragma unroll
    for (int i = 0; i < 4; i++) {
      af[i] = *(const s16x8*)&Al[(wr * 64 + i * 16 + (lane & 15)) * 40 + ((lane >> 4) << 3)];
      bf[i] = *(const s16x8*)&Bl[(wc * 64 + i * 16 + (lane & 15)) * 40 + ((lane >> 4) << 3)];
    }
#pragma unroll
    for (int i = 0; i < 4; i++)
#pragma unroll
      for (int j = 0; j < 4; j++)
        acc[i][j] = __builtin_amdgcn_mfma_f32_16x16x32_bf16(af[i], bf[j], acc[i][j], 0, 0, 0);
    __syncthreads();
  }
#pragma unroll
  for (int i = 0; i < 4; i++)
#pragma unroll
    for (int r = 0; r < 4; r++) {
      int orow = m0 + wr * 64 + i * 16 + ((lane >> 4) << 2) + r;
      float bias = proj_b[orow];
#pragma unroll
      for (int j = 0; j < 4; j++) {
        int ncol = n0 + wc * 64 + j * 16 + (lane & 15);
        out[((size_t)(b * 512 + orow)) * 4096 + ncol] = acc[i][j][r] + bias;
      }
    }
}

extern "C" void kernel_launch(void* const* d_in, const int* in_sizes, int n_in,
                              void* d_out, int out_size, void* d_ws, size_t ws_size,
                              hipStream_t stream) {
  const float* x      = (const float*)d_in[0];
  const float* qkv_w  = (const float*)d_in[1];
  const float* qkv_b  = (const float*)d_in[2];
  const float* proj_w = (const float*)d_in[3];
  const float* proj_b = (const float*)d_in[4];
  float* out = (float*)d_out;
  char* ws = (char*)d_ws;
  // ws layout (bytes): wq 1.5M | wp 0.5M | xt 8M | qk 16M | v 8M | ao 8M |
  //                    opart 16M | ml 1M  = ~59 MiB
  short* wq = (short*)(ws);
  short* wp = (short*)(ws + 1572864);
  short* xt = (short*)(ws + 2097152);
  short* qk = (short*)(ws + 10485760);
  short* vb = (short*)(ws + 27262976);
  short* ao = (short*)(ws + 35651584);
  short* op = (short*)(ws + 44040192);
  float* ml = (float*)(ws + 60817408);

  prep_weights  <<<1024, 256, 0, stream>>>(qkv_w, proj_w, wq, wp);
  prep_transpose<<<dim3(64, 8, 2), 256, 0, stream>>>(x, xt);
  qkv_gemm      <<<dim3(32, 12, 2), 256, 0, stream>>>(wq, xt, qkv_b, qk, vb);
  flash_attn    <<<1024, 256, 0, stream>>>(qk, vb, op, ml);
  merge_halves  <<<256, 256, 0, stream>>>(op, ml, ao);
  proj_gemm     <<<dim3(32, 4, 2), 256, 0, stream>>>(wp, ao, proj_b, out);
}

// Round 11
// 239.975 us; speedup vs baseline: 1.4758x; 1.0622x over previous
//
#include <hip/hip_runtime.h>

// ---------------------------------------------------------------------------
// SelfAttention: x[2,512,64,64] f32 -> qkv(1x1conv) -> 8-head attn (n=4096,d=64)
// -> proj -> out [2,512,4096] f32.
// R10: flash 142us (VALU essential-work floor in this structure); total 255.
// R11: port R10 staging to BOTH GEMMs — global_load_lds w16 (pre-swizzled
// source, linear LDS dest, conflict-free reads), double-buffer + 1 barrier
// per K-step, setprio around MFMA. Flash/merge/preps unchanged from R10.
// ---------------------------------------------------------------------------

#include <stdint.h>

typedef __attribute__((ext_vector_type(8))) short s16x8;    // 8 bf16 (4 VGPR)
typedef __attribute__((ext_vector_type(4))) float f32x4;    // 16x16 mfma C/D
typedef __attribute__((ext_vector_type(16))) float f32x16;  // 32x32 mfma C/D
typedef __attribute__((ext_vector_type(4))) unsigned short u16x4;
typedef __attribute__((ext_vector_type(2))) unsigned u32x2;
typedef __attribute__((ext_vector_type(4))) unsigned u32x4;

__device__ __forceinline__ unsigned short f2bf(float f) {
  unsigned u = __builtin_bit_cast(unsigned, f);
  u += 0x7fffu + ((u >> 16) & 1u);           // round-to-nearest-even
  return (unsigned short)(u >> 16);
}

__device__ __forceinline__ float bf2f(short s) {
  return __builtin_bit_cast(float, ((unsigned)(unsigned short)s) << 16);
}

__device__ __forceinline__ unsigned cvt_pk_bf16(float lo, float hi) {
  unsigned r;
  asm("v_cvt_pk_bf16_f32 %0, %1, %2" : "=v"(r) : "v"(lo), "v"(hi));
  return r;  // low16 = bf16(lo), high16 = bf16(hi)
}

// async global->LDS, 16B per lane; LDS dest = wave-uniform base + lane*16
__device__ __forceinline__ void gl_lds16(const void* g, void* l) {
  auto gp = reinterpret_cast<const __attribute__((address_space(1))) char*>(
      reinterpret_cast<uintptr_t>(g));
  auto lp = reinterpret_cast<__attribute__((address_space(3))) char*>(
      reinterpret_cast<uintptr_t>(l));
  __builtin_amdgcn_global_load_lds(gp, lp, 16, 0, 0);
}

// ---- kernel 0a: convert qkv_w (1536x512) and proj_w (512x512) f32->bf16 ----
__global__ __launch_bounds__(256) void prep_weights(
    const float* __restrict__ qkv_w, const float* __restrict__ proj_w,
    short* __restrict__ wq, short* __restrict__ wp) {
  int t = blockIdx.x * 256 + threadIdx.x;
  const int NQ = 1536 * 512 / 4;
  if (t < NQ) {
    float4 v = ((const float4*)qkv_w)[t];
    u16x4 o; o[0] = f2bf(v.x); o[1] = f2bf(v.y); o[2] = f2bf(v.z); o[3] = f2bf(v.w);
    ((u16x4*)wq)[t] = o;
  } else {
    int t2 = t - NQ;
    float4 v = ((const float4*)proj_w)[t2];
    u16x4 o; o[0] = f2bf(v.x); o[1] = f2bf(v.y); o[2] = f2bf(v.z); o[3] = f2bf(v.w);
    ((u16x4*)wp)[t2] = o;
  }
}

// ---- kernel 0b: x [b][c=512][n=4096] f32 -> Xt [b][n][c] bf16 ----
__global__ __launch_bounds__(256) void prep_transpose(
    const float* __restrict__ x, short* __restrict__ xt) {
  __shared__ short TL[64 * 72];
  const int b = blockIdx.z, c0 = blockIdx.y * 64, n0 = blockIdx.x * 64;
  const int t = threadIdx.x;
  const int cr = t >> 4, n4 = (t & 15) * 4;
#pragma unroll
  for (int i = 0; i < 4; i++) {
    int c = cr + i * 16;
    float4 v = *(const float4*)(x + ((size_t)(b * 512 + c0 + c)) * 4096 + n0 + n4);
    TL[(n4 + 0) * 72 + c] = (short)f2bf(v.x);
    TL[(n4 + 1) * 72 + c] = (short)f2bf(v.y);
    TL[(n4 + 2) * 72 + c] = (short)f2bf(v.z);
    TL[(n4 + 3) * 72 + c] = (short)f2bf(v.w);
  }
  __syncthreads();
  const int n = t >> 2;
#pragma unroll
  for (int s2 = 0; s2 < 2; s2++) {
    int s = (t & 3) * 2 + s2;
    s16x8 v = *(const s16x8*)&TL[n * 72 + s * 8];
    *(s16x8*)(xt + ((size_t)(b * 4096 + n0 + n)) * 512 + c0 + s * 8) = v;
  }
}

// ---- kernel 1: qkv GEMM v2 (global_load_lds + dbuf, 1 barrier/step) ----
// Q,K emitted [n][o] (swapped), V [o][n]. Q pre-scaled by 0.125*log2(e).
// LDS rows 64B (32 shorts); content[row][slot] = global[row][slot ^ (row&3)]
// (slot = 16B unit). Reads apply the same XOR -> conflict-free b128.
__global__ __launch_bounds__(256) void qkv_gemm(
    const short* __restrict__ wq, const short* __restrict__ xt,
    const float* __restrict__ qkv_b,
    short* __restrict__ qkbuf,   // [b][n][1024]  (Q cols 0..511 scaled, K 512..1023)
    short* __restrict__ vbuf) {  // [b][512][4096]
  __shared__ short Al[2][128 * 32];
  __shared__ short Bl[2][128 * 32];
  const int b = blockIdx.z;
  const int m0 = blockIdx.y * 128, n0 = blockIdx.x * 128;
  const bool swapped = (blockIdx.y < 8);
  const int t = threadIdx.x, lane = t & 63, wid = t >> 6;
  const int wr = wid >> 1, wc = wid & 1;
  // staging: wave covers 16 rows per issue; lane -> row wid*16+(lane>>2), slot lane&3
  const int rowoff = lane >> 2;
  const int srcswz = (((lane & 3) ^ (rowoff & 3)) << 4);   // bytes
  const char* gA = (const char*)(wq + (size_t)(m0 + wid * 16 + rowoff) * 512) + srcswz;
  const char* gB = (const char*)(xt + ((size_t)(b * 4096 + n0 + wid * 16 + rowoff)) * 512) + srcswz;
  char* lA0 = (char*)&Al[0][0] + (wid * 16) * 64;
  char* lA1 = (char*)&Al[1][0] + (wid * 16) * 64;
  char* lB0 = (char*)&Bl[0][0] + (wid * 16) * 64;
  char* lB1 = (char*)&Bl[1][0] + (wid * 16) * 64;

#define GISSUE(bi, ks)                                                      \
  do {                                                                      \
    gl_lds16(gA + (ks) * 64,         (bi) ? lA1 : lA0);                     \
    gl_lds16(gA + 65536 + (ks) * 64, ((bi) ? lA1 : lA0) + 64 * 64);         \
    gl_lds16(gB + (ks) * 64,         (bi) ? lB1 : lB0);                     \
    gl_lds16(gB + 65536 + (ks) * 64, ((bi) ? lB1 : lB0) + 64 * 64);         \
  } while (0)

  const int g4 = (lane >> 4) << 4;             // frag col byte (16B slot)
  const int rsw = (lane & 3) << 4;             // read swizzle (row&3 == lane&3)
  f32x4 acc[4][4] = {};

  GISSUE(0, 0);
#pragma unroll 1
  for (int ks = 0; ks < 16; ks++) {
    __syncthreads();                           // buf ks&1 ready; other buf reads done
    if (ks < 15) GISSUE((ks + 1) & 1, ks + 1);
    const int bi = ks & 1;
    const short* As = swapped ? Bl[bi] : Al[bi];
    const short* Bs = swapped ? Al[bi] : Bl[bi];
    s16x8 af[4], bf[4];
#pragma unroll
    for (int i = 0; i < 4; i++) {
      af[i] = *(const s16x8*)((const char*)As + (wr * 64 + i * 16 + (lane & 15)) * 64 + (g4 ^ rsw));
      bf[i] = *(const s16x8*)((const char*)Bs + (wc * 64 + i * 16 + (lane & 15)) * 64 + (g4 ^ rsw));
    }
    __builtin_amdgcn_s_setprio(1);
#pragma unroll
    for (int i = 0; i < 4; i++)
#pragma unroll
      for (int j = 0; j < 4; j++)
        acc[i][j] = __builtin_amdgcn_mfma_f32_16x16x32_bf16(af[i], bf[j], acc[i][j], 0, 0, 0);
    __builtin_amdgcn_s_setprio(0);
  }
#undef GISSUE
  if (!swapped) {                             // V region
#pragma unroll
    for (int i = 0; i < 4; i++)
#pragma unroll
      for (int r = 0; r < 4; r++) {
        int orow = m0 + wr * 64 + i * 16 + ((lane >> 4) << 2) + r;
        float bias = qkv_b[orow];
#pragma unroll
        for (int j = 0; j < 4; j++) {
          int ncol = n0 + wc * 64 + j * 16 + (lane & 15);
          vbuf[((size_t)(b * 512 + orow - 1024)) * 4096 + ncol] = (short)f2bf(acc[i][j][r] + bias);
        }
      }
  } else {                                    // Q/K region: D^T -> [n][o]
    const float qs = (m0 < 512) ? 0.18033688f : 1.0f;   // 0.125 * log2(e) for Q
#pragma unroll
    for (int j = 0; j < 4; j++) {
      int ocol = m0 + wc * 64 + j * 16 + (lane & 15);
      float bias = qkv_b[ocol];
#pragma unroll
      for (int i = 0; i < 4; i++)
#pragma unroll
        for (int r = 0; r < 4; r++) {
          int nrow = n0 + wr * 64 + i * 16 + ((lane >> 4) << 2) + r;
          qkbuf[((size_t)(b * 4096 + nrow)) * 1024 + ocol] = (short)f2bf((acc[i][j][r] + bias) * qs);
        }
    }
  }
}

// ---- kernel 2: flash attention v6 (unchanged from R10) ----
__global__ __launch_bounds__(256) void flash_attn(
    const short* __restrict__ qkbuf, const short* __restrict__ vbuf,
    short* __restrict__ opart,       // [2][16][4096][64] bf16
    float* __restrict__ mlbuf) {     // [2][16][4096][2] f32
  __shared__ short Kl[2][64 * 64];             // [buf][kpos][d]
  __shared__ short Vl[2][64 * 64];             // [buf][d][kpos]
  const int t = threadIdx.x, lane = t & 63, wid = t >> 6;
  const int hi = lane >> 5, q32 = lane & 31;
  const int j = blockIdx.x;
  const int lid = ((j & 7) << 7) + (j >> 3);   // XCD chunking, bijective 0..1023
  const int bh = lid >> 6, b = bh >> 3, h = bh & 7;
  const int rest = lid & 63;
  const int qc = rest >> 1, half = rest & 1;
  const int qb = qc * 128 + wid * 32;
  const int kt0 = half * 32;                   // this block's 32 kv tiles

  s16x8 qf[4];
  {
    const short* qrow = qkbuf + ((size_t)(b * 4096 + qb + q32)) * 1024 + h * 64 + hi * 8;
#pragma unroll
    for (int dc = 0; dc < 4; dc++) qf[dc] = *(const s16x8*)(qrow + dc * 16);
  }

  f32x16 oacc[2] = {};                         // O^T[d=di*32+(r&3)+8*(r>>2)+4*hi][q=q32]
  float m = -__builtin_inff();
  float l = 0.f;

  const int lrow = lane >> 3;
  const int lcolb = ((lane & 7) << 4) ^ (lrow << 4);
  const char* kp0 = (const char*)(qkbuf + ((size_t)(b * 4096 + kt0 * 64 + wid * 16 + lrow)) * 1024
                                  + 512 + h * 64) + lcolb;
  const char* kp1 = kp0 + 8 * 2048;            // +8 K rows
  const char* vp0 = (const char*)(vbuf + ((size_t)(b * 512 + h * 64 + wid * 16 + lrow)) * 4096
                                  + kt0 * 64) + lcolb;
  const char* vp1 = vp0 + 8 * 8192;            // +8 V rows

#define ISSUE_TILE(bi)                                                      \
  do {                                                                      \
    gl_lds16(kp0, &Kl[bi][(wid * 16 + 0) * 64]);                            \
    gl_lds16(kp1, &Kl[bi][(wid * 16 + 8) * 64]);                            \
    gl_lds16(vp0, &Vl[bi][(wid * 16 + 0) * 64]);                            \
    gl_lds16(vp1, &Vl[bi][(wid * 16 + 8) * 64]);                            \
    kp0 += 131072; kp1 += 131072; vp0 += 128; vp1 += 128;                   \
  } while (0)

  const int ksw = (q32 & 7) << 4;

  auto do_tile = [&](const short* Klb, const short* Vlb) {
#pragma unroll
    for (int kb = 0; kb < 2; kb++) {
      f32x16 st = {};
      const char* kr = (const char*)(Klb + (kb * 32 + q32) * 64);
      __builtin_amdgcn_s_setprio(1);
#pragma unroll
      for (int dc = 0; dc < 4; dc++) {
        s16x8 kf = *(const s16x8*)(kr + ((dc * 32 + hi * 16) ^ ksw));
        st = __builtin_amdgcn_mfma_f32_32x32x16_bf16(kf, qf[dc], st, 0, 0, 0);
      }
      __builtin_amdgcn_s_setprio(0);
      float x0 = fmaxf(st[0], st[1]),  x1 = fmaxf(st[2], st[3]);
      float x2 = fmaxf(st[4], st[5]),  x3 = fmaxf(st[6], st[7]);
      float x4 = fmaxf(st[8], st[9]),  x5 = fmaxf(st[10], st[11]);
      float x6 = fmaxf(st[12], st[13]), x7 = fmaxf(st[14], st[15]);
      x0 = fmaxf(x0, x1); x2 = fmaxf(x2, x3); x4 = fmaxf(x4, x5); x6 = fmaxf(x6, x7);
      x0 = fmaxf(x0, x2); x4 = fmaxf(x4, x6);
      float tm = fmaxf(x0, x4);
      tm = fmaxf(tm, __shfl_xor(tm, 32));
      if (!__all(tm <= m + 8.f)) {             // T13 defer-max
        float mn = fmaxf(m, tm);
        float alpha = exp2f(m - mn);
        m = mn;
        l *= alpha;
#pragma unroll
        for (int di = 0; di < 2; di++)
#pragma unroll
          for (int r2 = 0; r2 < 16; r2++) oacc[di][r2] *= alpha;
      }
      float p[16];
      float ps = 0.f;
#pragma unroll
      for (int r2 = 0; r2 < 16; r2++) { p[r2] = exp2f(st[r2] - m); ps += p[r2]; }
      l += ps;
#pragma unroll
      for (int kh = 0; kh < 2; kh++) {
        unsigned A  = cvt_pk_bf16(p[kh * 8 + 0], p[kh * 8 + 1]);
        unsigned Bu = cvt_pk_bf16(p[kh * 8 + 4], p[kh * 8 + 5]);
        unsigned C  = cvt_pk_bf16(p[kh * 8 + 2], p[kh * 8 + 3]);
        unsigned D  = cvt_pk_bf16(p[kh * 8 + 6], p[kh * 8 + 7]);
        u32x2 r0 = __builtin_amdgcn_permlane32_swap(A, Bu, false, false);
        u32x2 r1 = __builtin_amdgcn_permlane32_swap(C, D, false, false);
        u32x4 uu; uu[0] = r0[0]; uu[1] = r1[0]; uu[2] = r0[1]; uu[3] = r1[1];
        s16x8 pf = __builtin_bit_cast(s16x8, uu);
        __builtin_amdgcn_s_setprio(1);
#pragma unroll
        for (int di = 0; di < 2; di++) {
          const char* vr = (const char*)(Vlb + (di * 32 + q32) * 64);
          s16x8 vf = *(const s16x8*)(vr + ((kb * 64 + kh * 32 + hi * 16) ^ ksw));
          oacc[di] = __builtin_amdgcn_mfma_f32_32x32x16_bf16(vf, pf, oacc[di], 0, 0, 0);
        }
        __builtin_amdgcn_s_setprio(0);
      }
    }
  };

  ISSUE_TILE(0);
#pragma unroll 1
  for (int it = 0; it < 16; it++) {
    __syncthreads();
    ISSUE_TILE(1);
    do_tile(Kl[0], Vl[0]);
    __syncthreads();
    if (it < 15) ISSUE_TILE(0);
    do_tile(Kl[1], Vl[1]);
  }
#undef ISSUE_TILE

  l += __shfl_xor(l, 32);
  const size_t prow = ((size_t)(half * 16 + bh) * 4096 + qb + q32) * 64;
#pragma unroll
  for (int di = 0; di < 2; di++)
#pragma unroll
    for (int blk = 0; blk < 4; blk++) {
      uint2 w;
      w.x = cvt_pk_bf16(oacc[di][blk * 4 + 0], oacc[di][blk * 4 + 1]);
      w.y = cvt_pk_bf16(oacc[di][blk * 4 + 2], oacc[di][blk * 4 + 3]);
      *(uint2*)(opart + prow + di * 32 + blk * 8 + hi * 4) = w;
    }
  if (hi == 0) {
    const size_t mrow = (size_t)(half * 16 + bh) * 4096 + qb + q32;
    ((float2*)mlbuf)[mrow] = make_float2(m, l);
  }
}

// ---- kernel 2b: merge the two kv-half partials -> aout bf16 [b][n][512] ----
__global__ __launch_bounds__(256) void merge_halves(
    const short* __restrict__ opart, const float* __restrict__ mlbuf,
    short* __restrict__ aout) {
  const int row = blockIdx.x * 256 + threadIdx.x;  // 65536 rows (bh*4096+q)
  const int bh = row >> 12, q = row & 4095, b = bh >> 3, h = bh & 7;
  float2 ml0 = ((const float2*)mlbuf)[row];
  float2 ml1 = ((const float2*)mlbuf)[65536 + row];
  float mm = fmaxf(ml0.x, ml1.x);
  float w0 = exp2f(ml0.x - mm), w1 = exp2f(ml1.x - mm);
  float inv = 1.f / (w0 * ml0.y + w1 * ml1.y);
  w0 *= inv; w1 *= inv;
  const s16x8* r0 = (const s16x8*)(opart + (size_t)row * 64);
  const s16x8* r1 = (const s16x8*)(opart + ((size_t)65536 + row) * 64);
  short* po = aout + ((size_t)(b * 4096 + q)) * 512 + h * 64;
#pragma unroll
  for (int sg = 0; sg < 8; sg++) {
    s16x8 a0 = r0[sg], a1 = r1[sg];
    float v[8];
#pragma unroll
    for (int i = 0; i < 8; i++) v[i] = w0 * bf2f(a0[i]) + w1 * bf2f(a1[i]);
    u32x4 uu;
#pragma unroll
    for (int k = 0; k < 4; k++) uu[k] = cvt_pk_bf16(v[2 * k], v[2 * k + 1]);
    *(s16x8*)(po + sg * 8) = __builtin_bit_cast(s16x8, uu);
  }
}

// ---- kernel 3: proj GEMM v2 (same staging upgrade) ----
__global__ __launch_bounds__(256) void proj_gemm(
    const short* __restrict__ wp, const short* __restrict__ aout,
    const float* __restrict__ proj_b, float* __restrict__ out) {
  __shared__ short Al[2][128 * 32];
  __shared__ short Bl[2][128 * 32];
  const int b = blockIdx.z;
  const int m0 = blockIdx.y * 128, n0 = blockIdx.x * 128;
  const int t = threadIdx.x, lane = t & 63, wid = t >> 6;
  const int wr = wid >> 1, wc = wid & 1;
  const int rowoff = lane >> 2;
  const int srcswz = (((lane & 3) ^ (rowoff & 3)) << 4);
  const char* gA = (const char*)(wp + (size_t)(m0 + wid * 16 + rowoff) * 512) + srcswz;
  const char* gB = (const char*)(aout + ((size_t)(b * 4096 + n0 + wid * 16 + rowoff)) * 512) + srcswz;
  char* lA0 = (char*)&Al[0][0] + (wid * 16) * 64;
  char* lA1 = (char*)&Al[1][0] + (wid * 16) * 64;
  char* lB0 = (char*)&Bl[0][0] + (wid * 16) * 64;
  char* lB1 = (char*)&Bl[1][0] + (wid * 16) * 64;

#define GISSUE(bi, ks)                                                      \
  do {                                                                      \
    gl_lds16(gA + (ks) * 64,         (bi) ? lA1 : lA0);                     \
    gl_lds16(gA + 65536 + (ks) * 64, ((bi) ? lA1 : lA0) + 64 * 64);         \
    gl_lds16(gB + (ks) * 64,         (bi) ? lB1 : lB0);                     \
    gl_lds16(gB + 65536 + (ks) * 64, ((bi) ? lB1 : lB0) + 64 * 64);         \
  } while (0)

  const int g4 = (lane >> 4) << 4;
  const int rsw = (lane & 3) << 4;
  f32x4 acc[4][4] = {};

  GISSUE(0, 0);
#pragma unroll 1
  for (int ks = 0; ks < 16; ks++) {
    __syncthreads();
    if (ks < 15) GISSUE((ks + 1) & 1, ks + 1);
    const int bi = ks & 1;
    s16x8 af[4], bf[4];
#pragma unroll
    for (int i = 0; i < 4; i++) {
      af[i] = *(const s16x8*)((const char*)Al[bi] + (wr * 64 + i * 16 + (lane & 15)) * 64 + (g4 ^ rsw));
      bf[i] = *(const s16x8*)((const char*)Bl[bi] + (wc * 64 + i * 16 + (lane & 15)) * 64 + (g4 ^ rsw));
    }
    __builtin_amdgcn_s_setprio(1);
#pragma unroll
    for (int i = 0; i < 4; i++)
#pragma unroll
      for (int j = 0; j < 4; j++)
        acc[i][j] = __builtin_amdgcn_mfma_f32_16x16x32_bf16(af[i], bf[j], acc[i][j], 0, 0, 0);
    __builtin_amdgcn_s_setprio(0);
  }
#undef GISSUE
#pragma unroll
  for (int i = 0; i < 4; i++)
#pragma unroll
    for (int r = 0; r < 4; r++) {
      int orow = m0 + wr * 64 + i * 16 + ((lane >> 4) << 2) + r;
      float bias = proj_b[orow];
#pragma unroll
      for (int j = 0; j < 4; j++) {
        int ncol = n0 + wc * 64 + j * 16 + (lane & 15);
        out[((size_t)(b * 512 + orow)) * 4096 + ncol] = acc[i][j][r] + bias;
      }
    }
}

extern "C" void kernel_launch(void* const* d_in, const int* in_sizes, int n_in,
                              void* d_out, int out_size, void* d_ws, size_t ws_size,
                              hipStream_t stream) {
  const float* x      = (const float*)d_in[0];
  const float* qkv_w  = (const float*)d_in[1];
  const float* qkv_b  = (const float*)d_in[2];
  const float* proj_w = (const float*)d_in[3];
  const float* proj_b = (const float*)d_in[4];
  float* out = (float*)d_out;
  char* ws = (char*)d_ws;
  // ws layout (bytes): wq 1.5M | wp 0.5M | xt 8M | qk 16M | v 8M | ao 8M |
  //                    opart 16M | ml 1M  = ~59 MiB
  short* wq = (short*)(ws);
  short* wp = (short*)(ws + 1572864);
  short* xt = (short*)(ws + 2097152);
  short* qk = (short*)(ws + 10485760);
  short* vb = (short*)(ws + 27262976);
  short* ao = (short*)(ws + 35651584);
  short* op = (short*)(ws + 44040192);
  float* ml = (float*)(ws + 60817408);

  prep_weights  <<<1024, 256, 0, stream>>>(qkv_w, proj_w, wq, wp);
  prep_transpose<<<dim3(64, 8, 2), 256, 0, stream>>>(x, xt);
  qkv_gemm      <<<dim3(32, 12, 2), 256, 0, stream>>>(wq, xt, qkv_b, qk, vb);
  flash_attn    <<<1024, 256, 0, stream>>>(qk, vb, op, ml);
  merge_halves  <<<256, 256, 0, stream>>>(op, ml, ao);
  proj_gemm     <<<dim3(32, 4, 2), 256, 0, stream>>>(wp, ao, proj_b, out);
}